// Round 2
// 200.159 us; speedup vs baseline: 1.0310x; 1.0310x over previous
//
#include <hip/hip_runtime.h>

typedef __bf16 bf16x8 __attribute__((ext_vector_type(8)));
typedef __bf16 bf16x4 __attribute__((ext_vector_type(4)));
typedef __bf16 bf16x2 __attribute__((ext_vector_type(2)));
typedef float f32x4 __attribute__((ext_vector_type(4)));
typedef float f32x16 __attribute__((ext_vector_type(16)));
typedef int i32x4 __attribute__((ext_vector_type(4)));
typedef unsigned int u32x2 __attribute__((ext_vector_type(2)));

__device__ __forceinline__ void async16(void* lds, const void* g) {
  __builtin_amdgcn_global_load_lds(
      (__attribute__((address_space(1))) unsigned int*)(g),
      (__attribute__((address_space(3))) unsigned int*)(lds), 16, 0, 0);
}

__device__ __forceinline__ unsigned int pack2(float a, float b) {
  bf16x2 t;
  t[0] = (__bf16)a;
  t[1] = (__bf16)b;
  return __builtin_bit_cast(unsigned int, t);
}

// lane[i] <-> lane[i+32] half-wave exchange: d.hi <-> s.lo.
__device__ __forceinline__ void plswap(unsigned int& d, unsigned int& s) {
#if __has_builtin(__builtin_amdgcn_permlane32_swap)
  u32x2 r = __builtin_amdgcn_permlane32_swap(d, s, false, false);
  d = r[0];
  s = r[1];
#else
  asm("v_permlane32_swap_b32 %0, %1" : "+v"(d), "+v"(s));
#endif
}

// Per-block dtype self-detect on a 2048-u16 window.
__device__ __forceinline__ int detect_block(const unsigned short* win, int* cnt_sh) {
  if (threadIdx.x == 0) *cnt_sh = 0;
  __syncthreads();
  int c = 0;
#pragma unroll
  for (int j = 0; j < 8; j++) {
    const unsigned short u = win[threadIdx.x * 8 + j];
    if (((u >> 7) & 0xFF) >= 0xC0) c++;
  }
  if (c) atomicAdd(cnt_sh, c);
  __syncthreads();
  return (*cnt_sh >= 64) ? 1 : 0;
}

// ---------------- prep: x->bf16 cvt (blocks 0..2047) + Wqkv transpose
// (2048..2815) + Wout transpose (2816..3071), all self-detecting dtype.
__global__ __launch_bounds__(256) void prep(
    const void* __restrict__ x, const void* __restrict__ Wqkv,
    const void* __restrict__ Wout, __bf16* __restrict__ xb,
    __bf16* __restrict__ WqkvT, __bf16* __restrict__ WoutT,
    int* __restrict__ flagp)
{
  __shared__ __bf16 tile[64 * 65];
  __shared__ int cnt;
  const int bx = blockIdx.x;
  const int t = threadIdx.x;

  if (bx < 2048) {
    const long base = (long)bx * 2048;
    const int f = detect_block((const unsigned short*)x + base, &cnt);
    if (bx == 0 && t == 0) *flagp = f;
    const long i = base + t * 8;
    if (f) {
      const float* s = (const float*)x;
#pragma unroll
      for (int j = 0; j < 8; j++) xb[i + j] = (__bf16)s[i + j];
    } else {
      *(bf16x8*)&xb[i] = *(const bf16x8*)((const __bf16*)x + i);
    }
    return;
  }

  const void* in;  __bf16* out;  int R = 1024, C, tcx, tr;
  if (bx < 2816) {
    const int idx = bx - 2048;
    in = Wqkv; out = WqkvT; C = 3072; tcx = (idx % 48) * 64; tr = (idx / 48) * 64;
  } else {
    const int idx = bx - 2816;
    in = Wout; out = WoutT; C = 1024; tcx = (idx % 16) * 64; tr = (idx / 16) * 64;
  }
  const int f = detect_block((const unsigned short*)in + (long)tr * C + tcx, &cnt);
#pragma unroll
  for (int i = 0; i < 16; i++) {
    const int idx = t + 256 * i;
    const int r = idx >> 6, c = idx & 63;
    const long g = (long)(tr + r) * C + tcx + c;
    tile[r * 65 + c] = f ? (__bf16)((const float*)in)[g] : ((const __bf16*)in)[g];
  }
  __syncthreads();
#pragma unroll
  for (int i = 0; i < 16; i++) {
    const int idx = t + 256 * i;
    const int r = idx >> 6, c = idx & 63;
    out[(long)(tcx + r) * R + tr + c] = tile[c * 65 + r];
  }
}

// ---------------- qkv GEMM: [4096,1024] x [1024,3072]^T, prefetch-pipelined.
// Q,K -> qk (stride 2048); V -> Vt[bh*64+d][2048] via padded-LDS transpose.
__global__ __launch_bounds__(256, 3) void gemm_qkv(
    const __bf16* __restrict__ A, const __bf16* __restrict__ Bt,
    __bf16* __restrict__ Cqk, __bf16* __restrict__ Vt)
{
  __shared__ __bf16 smem[17408];
  const int t = threadIdx.x;
  const int l = t & 63;
  const int w = t >> 6;
  const int wr = w >> 1, wc = w & 1;
  const long m0 = (long)blockIdx.x * 128;
  const long n0 = (long)blockIdx.y * 128;
  const int K = 1024;

  const int srow = w * 16 + (l >> 2);
  const int skof = (l & 3) * 8;
  const __bf16* gA = A + (m0 + srow) * (long)K + skof;
  const __bf16* gB = Bt + (n0 + srow) * (long)K + skof;
  const int Ao[2] = {0, 8192}, Bo[2] = {4096, 12288};
  const int lof = w * 512 + l * 8;

  async16(smem + Ao[0] + lof,        gA);
  async16(smem + Ao[0] + 2048 + lof, gA + 64 * (long)K);
  async16(smem + Bo[0] + lof,        gB);
  async16(smem + Bo[0] + 2048 + lof, gB + 64 * (long)K);
  gA += 32; gB += 32;
  __syncthreads();

  f32x4 acc[4][4] = {};

  for (int it = 0; it < 32; it++) {
    if (it < 31) {
      const int nb = (it + 1) & 1;
      async16(smem + Ao[nb] + lof,        gA);
      async16(smem + Ao[nb] + 2048 + lof, gA + 64 * (long)K);
      async16(smem + Bo[nb] + lof,        gB);
      async16(smem + Bo[nb] + 2048 + lof, gB + 64 * (long)K);
      gA += 32; gB += 32;
    }
    const __bf16* As = smem + Ao[it & 1];
    const __bf16* Bs = smem + Bo[it & 1];
    bf16x8 af[4], bfr[4];
#pragma unroll
    for (int mi = 0; mi < 4; mi++)
      af[mi] = *(const bf16x8*)&As[(wr * 64 + mi * 16 + (l & 15)) * 32 + (l >> 4) * 8];
#pragma unroll
    for (int ni = 0; ni < 4; ni++)
      bfr[ni] = *(const bf16x8*)&Bs[(wc * 64 + ni * 16 + (l & 15)) * 32 + (l >> 4) * 8];
#pragma unroll
    for (int mi = 0; mi < 4; mi++)
#pragma unroll
      for (int ni = 0; ni < 4; ni++)
        acc[mi][ni] = __builtin_amdgcn_mfma_f32_16x16x32_bf16(af[mi], bfr[ni], acc[mi][ni], 0, 0, 0);
    __syncthreads();
  }

  if (n0 < 2048) {
#pragma unroll
    for (int mi = 0; mi < 4; mi++)
#pragma unroll
      for (int ni = 0; ni < 4; ni++) {
        const long col = n0 + wc * 64 + ni * 16 + (l & 15);
#pragma unroll
        for (int r = 0; r < 4; r++) {
          const long row = m0 + wr * 64 + mi * 16 + (l >> 4) * 4 + r;
          Cqk[row * 2048 + col] = (__bf16)acc[mi][ni][r];
        }
      }
  } else {
#pragma unroll
    for (int mi = 0; mi < 4; mi++)
#pragma unroll
      for (int ni = 0; ni < 4; ni++) {
        const int c = wc * 64 + ni * 16 + (l & 15);
        const int r = wr * 64 + mi * 16 + (l >> 4) * 4;
        bf16x4 pk;
#pragma unroll
        for (int k = 0; k < 4; k++) pk[k] = (__bf16)acc[mi][ni][k];
        *(bf16x4*)&smem[c * 136 + r] = pk;
      }
    __syncthreads();
    const int b = (int)(m0 >> 11);
    const int nbase = (int)(m0 & 2047);
#pragma unroll
    for (int i = 0; i < 8; i++) {
      const int c = (t >> 4) + i * 16;
      const int r8 = (t & 15) * 8;
      const bf16x8 v = *(const bf16x8*)&smem[c * 136 + r8];
      const int vcol = (int)(n0 - 2048) + c;
      *(bf16x8*)&Vt[((long)(b * 16 + (vcol >> 6)) * 64 + (vcol & 63)) * 2048 + nbase + r8] = v;
    }
  }
}

// ---------------- out GEMM: [4096,1024] x [1024,1024]^T + bias, 128x64 tile.
__global__ __launch_bounds__(256, 2) void gemm_out(
    const __bf16* __restrict__ A, const __bf16* __restrict__ Bt,
    const void* __restrict__ bias_raw, void* __restrict__ C,
    const int* __restrict__ flagp)
{
  __shared__ __bf16 smem[12288];
  const int t = threadIdx.x;
  const int l = t & 63;
  const int w = t >> 6;
  const int wr = w >> 1, wc = w & 1;
  const long m0 = (long)blockIdx.x * 128;
  const long n0 = (long)blockIdx.y * 64;
  const int of = *flagp;
  const int K = 1024;

  const int srow = w * 16 + (l >> 2);
  const int skof = (l & 3) * 8;
  const __bf16* gA = A + (m0 + srow) * (long)K + skof;
  const __bf16* gB = Bt + (n0 + srow) * (long)K + skof;
  const int Ao[2] = {0, 6144}, Bo[2] = {4096, 10240};
  const int lof = w * 512 + l * 8;

  async16(smem + Ao[0] + lof,        gA);
  async16(smem + Ao[0] + 2048 + lof, gA + 64 * (long)K);
  async16(smem + Bo[0] + lof,        gB);
  gA += 32; gB += 32;
  __syncthreads();

  f32x4 acc[4][2] = {};

  for (int it = 0; it < 32; it++) {
    if (it < 31) {
      const int nb = (it + 1) & 1;
      async16(smem + Ao[nb] + lof,        gA);
      async16(smem + Ao[nb] + 2048 + lof, gA + 64 * (long)K);
      async16(smem + Bo[nb] + lof,        gB);
      gA += 32; gB += 32;
    }
    const __bf16* As = smem + Ao[it & 1];
    const __bf16* Bs = smem + Bo[it & 1];
    bf16x8 af[4], bfr[2];
#pragma unroll
    for (int mi = 0; mi < 4; mi++)
      af[mi] = *(const bf16x8*)&As[(wr * 64 + mi * 16 + (l & 15)) * 32 + (l >> 4) * 8];
#pragma unroll
    for (int ni = 0; ni < 2; ni++)
      bfr[ni] = *(const bf16x8*)&Bs[(wc * 32 + ni * 16 + (l & 15)) * 32 + (l >> 4) * 8];
#pragma unroll
    for (int mi = 0; mi < 4; mi++)
#pragma unroll
      for (int ni = 0; ni < 2; ni++)
        acc[mi][ni] = __builtin_amdgcn_mfma_f32_16x16x32_bf16(af[mi], bfr[ni], acc[mi][ni], 0, 0, 0);
    __syncthreads();
  }

#pragma unroll
  for (int mi = 0; mi < 4; mi++)
#pragma unroll
    for (int ni = 0; ni < 2; ni++) {
      const long col = n0 + wc * 32 + ni * 16 + (l & 15);
      const float bv = of ? ((const float*)bias_raw)[col]
                          : (float)((const __bf16*)bias_raw)[col];
#pragma unroll
      for (int r = 0; r < 4; r++) {
        const long row = m0 + wr * 64 + mi * 16 + (l >> 4) * 4 + r;
        const float val = acc[mi][ni][r] + bv;
        const long off = row * 1024 + col;
        if (of) ((float*)C)[off] = val;
        else    ((__bf16*)C)[off] = (__bf16)val;
      }
    }
}

// ---------------- flash attention, register-resident P (T12 structure).
// Each wave (wi,wj) computes St[j in wj-half][i in wi-half] (A=K rows,
// B=Q rows), keeps P in registers, and accumulates PARTIAL
// O[i in wi-half][all 64 d] over its own j-half only (k=32 per tile).
// The cross-half j exchange inside the wave uses bf16 packs +
// permlane32_swap (T12 pairing, re-derived: A-fragment lane l needs
// P[i=l&31][j=hl*8+e]; swap(pack(st0,st1),pack(st4,st5)) yields W0/W2 for
// both half-waves). The wj-pair partial-O sum happens ONCE in the epilogue
// via LDS (dead K/V buffers), not per tile. Q fragments come straight from
// global (L2-hot, one-time) -> no Q/Ps LDS region, 32KB LDS, ONE barrier
// per K/V tile (prefetch drain only), prefetch issued right after it.
#define EXP2_SCALE 0.045084439f   // (1/32) * log2(e)

__global__ __launch_bounds__(256, 4) void attn_kernel(
    const __bf16* __restrict__ qk, const __bf16* __restrict__ Vt,
    __bf16* __restrict__ O)
{
  __shared__ __bf16 smem[16384];   // K0@0 V0@4096 K1@8192 V1@12288 (elements)
  const int t = threadIdx.x;
  const int l = t & 63;
  const int w = t >> 6;
  const int wi = w & 1, wj = w >> 1;
  const int hl = l >> 5;
  const int i7 = l & 7;
  // XCD swizzle: same bh => same (linear % 8) => same XCD L2.
  const int L = blockIdx.y * 32 + blockIdx.x;
  const int bh = (L & 7) * 4 + ((L >> 3) & 3);
  const int qt = L >> 5;
  const int b = bh >> 4, head = bh & 15;
  const long q_row0 = (long)b * 2048 + qt * 64;

  const int srow = w * 8 + (l >> 3);
  const int sdof = ((l & 7) ^ (l >> 3)) * 8;
  const int lof = w * 512 + l * 8;

  // prolog: tile 0 K/V staging
  const __bf16* gK = qk + ((long)b * 2048 + srow) * 2048 + 1024 + head * 64 + sdof;
  const __bf16* gV = Vt + ((long)bh * 64 + srow) * 2048 + sdof;
  async16(smem + lof,        gK);
  async16(smem + 2048 + lof, gK + 32 * 2048);
  async16(smem + 4096 + lof, gV);
  async16(smem + 6144 + lof, gV + 32 * 2048);
  gK += (long)64 * 2048;
  gV += 64;

  // Q fragments direct from global (rows wi*32+(l&31), k-elems hl*8 per chunk)
  bf16x8 qf[4];
  {
    const __bf16* gQ = qk + (q_row0 + wi * 32 + (l & 31)) * 2048 + head * 64 + hl * 8;
#pragma unroll
    for (int kc = 0; kc < 4; kc++)
      qf[kc] = *(const bf16x8*)(gQ + kc * 16);
  }

  f32x16 accA = {0,0,0,0,0,0,0,0,0,0,0,0,0,0,0,0};  // d 0..31
  f32x16 accB = {0,0,0,0,0,0,0,0,0,0,0,0,0,0,0,0};  // d 32..63
  float l_i = 0.0f;

  for (int it = 0; it < 32; it++) {
    __syncthreads();               // drains prefetch for cur (all waves)
    if (it < 31) {
      const int nb = ((it + 1) & 1) * 8192;
      async16(smem + nb + lof,        gK);
      async16(smem + nb + 2048 + lof, gK + 32 * 2048);
      async16(smem + nb + 4096 + lof, gV);
      async16(smem + nb + 6144 + lof, gV + 32 * 2048);
      gK += (long)64 * 2048;
      gV += 64;
    }
    const __bf16* Ks = smem + (it & 1) * 8192;
    const __bf16* Vs = Ks + 4096;

    // St[j in wj-half][i in wi-half]
    f32x16 st = {0,0,0,0,0,0,0,0,0,0,0,0,0,0,0,0};
    __builtin_amdgcn_s_setprio(1);
#pragma unroll
    for (int kc = 0; kc < 4; kc++) {
      const bf16x8 ak = *(const bf16x8*)&Ks[(wj * 32 + (l & 31)) * 64 + (((kc * 2 + hl) ^ i7) * 8)];
      st = __builtin_amdgcn_mfma_f32_32x32x16_bf16(ak, qf[kc], st, 0, 0, 0);
    }
    __builtin_amdgcn_s_setprio(0);

    // exp + row-sum (lane owns 16 scores of query i = wi*32+(l&31); regs
    // cover j_off = (r&3)+8*(r>>2)+4*hl within this wave's wj-half)
    float rs = 0.0f;
#pragma unroll
    for (int r = 0; r < 16; r++) {
      const float p = exp2f(st[r] * EXP2_SCALE);
      st[r] = p;
      rs += p;
    }
    rs += __shfl_xor(rs, 32, 64);
    l_i += rs;

    // in-register P -> bf16 A-fragments for this wave's 32 j's (2 chunks).
    unsigned int a0 = pack2(st[0],  st[1]),  b0 = pack2(st[4],  st[5]);
    unsigned int c0 = pack2(st[2],  st[3]),  d0 = pack2(st[6],  st[7]);
    unsigned int a1 = pack2(st[8],  st[9]),  b1 = pack2(st[12], st[13]);
    unsigned int c1 = pack2(st[10], st[11]), d1 = pack2(st[14], st[15]);
    plswap(a0, b0);
    plswap(c0, d0);
    plswap(a1, b1);
    plswap(c1, d1);
    const i32x4 f0 = {(int)a0, (int)c0, (int)b0, (int)d0};
    const i32x4 f1 = {(int)a1, (int)c1, (int)b1, (int)d1};
    const bf16x8 pa0 = __builtin_bit_cast(bf16x8, f0);
    const bf16x8 pa1 = __builtin_bit_cast(bf16x8, f1);

    // partial O[i in wi-half][d 0..63] over own j-half (k=32: 2 chunks)
    const int vg = wj * 4;
    const bf16x8 bv00 = *(const bf16x8*)&Vs[((l & 31)) * 64      + (((vg + hl) ^ i7) * 8)];
    const bf16x8 bv01 = *(const bf16x8*)&Vs[(32 + (l & 31)) * 64 + (((vg + hl) ^ i7) * 8)];
    const bf16x8 bv10 = *(const bf16x8*)&Vs[((l & 31)) * 64      + (((vg + 2 + hl) ^ i7) * 8)];
    const bf16x8 bv11 = *(const bf16x8*)&Vs[(32 + (l & 31)) * 64 + (((vg + 2 + hl) ^ i7) * 8)];
    __builtin_amdgcn_s_setprio(1);
    accA = __builtin_amdgcn_mfma_f32_32x32x16_bf16(pa0, bv00, accA, 0, 0, 0);
    accB = __builtin_amdgcn_mfma_f32_32x32x16_bf16(pa0, bv01, accB, 0, 0, 0);
    accA = __builtin_amdgcn_mfma_f32_32x32x16_bf16(pa1, bv10, accA, 0, 0, 0);
    accB = __builtin_amdgcn_mfma_f32_32x32x16_bf16(pa1, bv11, accB, 0, 0, 0);
    __builtin_amdgcn_s_setprio(0);
  }

  // epilogue: combine partial O across the wj pair + l_i across wj, store.
  __syncthreads();                       // all tile reads done; LDS reusable
  float* xbf = (float*)smem;             // 4 waves x 1024 f32 = 16KB
  float* lb  = (float*)(smem + 8192);    // 128 floats (bytes 16384..16896)
#pragma unroll
  for (int r = 0; r < 16; r++)           // publish the OTHER d-half partial
    xbf[w * 1024 + r * 64 + l] = wj ? accA[r] : accB[r];
  if (l < 32) lb[w * 32 + l] = l_i;
  __syncthreads();
  const int pw = 2 * (1 - wj) + wi;      // partner wave (same wi, other wj)
#pragma unroll
  for (int r = 0; r < 16; r++) {
    const int iloc = (r & 3) + 8 * (r >> 2) + 4 * hl;
    const float lt = lb[wi * 32 + iloc] + lb[(wi + 2) * 32 + iloc];
    const float own = wj ? accB[r] : accA[r];
    const float o = own + xbf[pw * 1024 + r * 64 + l];
    const long row = q_row0 + wi * 32 + iloc;
    const long col = (long)head * 64 + wj * 32 + (l & 31);
    O[row * 1024 + col] = (__bf16)(o / lt);
  }
}

extern "C" void kernel_launch(void* const* d_in, const int* in_sizes, int n_in,
                              void* d_out, int out_size, void* d_ws, size_t ws_size,
                              hipStream_t stream) {
  const void* x    = d_in[0];
  const void* Wqkv = d_in[1];
  const void* Wout = d_in[2];
  const void* bout = d_in[3];

  char* ws = (char*)d_ws;
  int*    flagp = (int*)ws;
  __bf16* xb    = (__bf16*)(ws + 4096);                      // 8 MB (dead after gemm_qkv)
  __bf16* Obuf  = xb;                                        // alias
  __bf16* WqkvT = (__bf16*)(ws + 4096 +  8388608);           // 6 MB
  __bf16* WoutT = (__bf16*)(ws + 4096 + 14680064);           // 2 MB
  __bf16* qkbuf = (__bf16*)(ws + 4096 + 16777216);           // 16 MB
  __bf16* VtBuf = (__bf16*)(ws + 4096 + 33554432);           // 8 MB

  hipLaunchKernelGGL(prep, dim3(3072), dim3(256), 0, stream,
                     x, Wqkv, Wout, xb, WqkvT, WoutT, flagp);
  hipLaunchKernelGGL(gemm_qkv, dim3(32, 24), dim3(256), 0, stream,
                     xb, WqkvT, qkbuf, VtBuf);
  hipLaunchKernelGGL(attn_kernel, dim3(32, 32), dim3(256), 0, stream,
                     qkbuf, VtBuf, Obuf);
  hipLaunchKernelGGL(gemm_out, dim3(32, 16), dim3(256), 0, stream,
                     Obuf, WoutT, bout, d_out, flagp);
}

// Round 3
// 200.067 us; speedup vs baseline: 1.0315x; 1.0005x over previous
//
#include <hip/hip_runtime.h>

typedef __bf16 bf16x8 __attribute__((ext_vector_type(8)));
typedef __bf16 bf16x4 __attribute__((ext_vector_type(4)));
typedef __bf16 bf16x2 __attribute__((ext_vector_type(2)));
typedef float f32x4 __attribute__((ext_vector_type(4)));
typedef float f32x16 __attribute__((ext_vector_type(16)));
typedef int i32x4 __attribute__((ext_vector_type(4)));
typedef unsigned int u32x2 __attribute__((ext_vector_type(2)));

__device__ __forceinline__ void async16(void* lds, const void* g) {
  __builtin_amdgcn_global_load_lds(
      (__attribute__((address_space(1))) unsigned int*)(g),
      (__attribute__((address_space(3))) unsigned int*)(lds), 16, 0, 0);
}

__device__ __forceinline__ unsigned int pack2(float a, float b) {
  bf16x2 t;
  t[0] = (__bf16)a;
  t[1] = (__bf16)b;
  return __builtin_bit_cast(unsigned int, t);
}

// lane[i] <-> lane[i+32] half-wave exchange: d.hi <-> s.lo.
__device__ __forceinline__ void plswap(unsigned int& d, unsigned int& s) {
#if __has_builtin(__builtin_amdgcn_permlane32_swap)
  u32x2 r = __builtin_amdgcn_permlane32_swap(d, s, false, false);
  d = r[0];
  s = r[1];
#else
  asm("v_permlane32_swap_b32 %0, %1" : "+v"(d), "+v"(s));
#endif
}

// Per-block dtype self-detect on a 2048-u16 window.
__device__ __forceinline__ int detect_block(const unsigned short* win, int* cnt_sh) {
  if (threadIdx.x == 0) *cnt_sh = 0;
  __syncthreads();
  int c = 0;
#pragma unroll
  for (int j = 0; j < 8; j++) {
    const unsigned short u = win[threadIdx.x * 8 + j];
    if (((u >> 7) & 0xFF) >= 0xC0) c++;
  }
  if (c) atomicAdd(cnt_sh, c);
  __syncthreads();
  return (*cnt_sh >= 64) ? 1 : 0;
}

// ---------------- prep: x->bf16 cvt (blocks 0..2047) + Wqkv transpose
// (2048..2815) + Wout transpose (2816..3071), all self-detecting dtype.
__global__ __launch_bounds__(256) void prep(
    const void* __restrict__ x, const void* __restrict__ Wqkv,
    const void* __restrict__ Wout, __bf16* __restrict__ xb,
    __bf16* __restrict__ WqkvT, __bf16* __restrict__ WoutT,
    int* __restrict__ flagp)
{
  __shared__ __bf16 tile[64 * 65];
  __shared__ int cnt;
  const int bx = blockIdx.x;
  const int t = threadIdx.x;

  if (bx < 2048) {
    const long base = (long)bx * 2048;
    const int f = detect_block((const unsigned short*)x + base, &cnt);
    if (bx == 0 && t == 0) *flagp = f;
    const long i = base + t * 8;
    if (f) {
      const float* s = (const float*)x;
#pragma unroll
      for (int j = 0; j < 8; j++) xb[i + j] = (__bf16)s[i + j];
    } else {
      *(bf16x8*)&xb[i] = *(const bf16x8*)((const __bf16*)x + i);
    }
    return;
  }

  const void* in;  __bf16* out;  int R = 1024, C, tcx, tr;
  if (bx < 2816) {
    const int idx = bx - 2048;
    in = Wqkv; out = WqkvT; C = 3072; tcx = (idx % 48) * 64; tr = (idx / 48) * 64;
  } else {
    const int idx = bx - 2816;
    in = Wout; out = WoutT; C = 1024; tcx = (idx % 16) * 64; tr = (idx / 16) * 64;
  }
  const int f = detect_block((const unsigned short*)in + (long)tr * C + tcx, &cnt);
#pragma unroll
  for (int i = 0; i < 16; i++) {
    const int idx = t + 256 * i;
    const int r = idx >> 6, c = idx & 63;
    const long g = (long)(tr + r) * C + tcx + c;
    tile[r * 65 + c] = f ? (__bf16)((const float*)in)[g] : ((const __bf16*)in)[g];
  }
  __syncthreads();
#pragma unroll
  for (int i = 0; i < 16; i++) {
    const int idx = t + 256 * i;
    const int r = idx >> 6, c = idx & 63;
    out[(long)(tcx + r) * R + tr + c] = tile[c * 65 + r];
  }
}

// ---------------- qkv GEMM: [4096,1024] x [1024,3072]^T, prefetch-pipelined.
// Q,K -> qk (stride 2048); V -> Vt[bh*64+d][2048] via padded-LDS transpose.
__global__ __launch_bounds__(256, 3) void gemm_qkv(
    const __bf16* __restrict__ A, const __bf16* __restrict__ Bt,
    __bf16* __restrict__ Cqk, __bf16* __restrict__ Vt)
{
  __shared__ __bf16 smem[17408];
  const int t = threadIdx.x;
  const int l = t & 63;
  const int w = t >> 6;
  const int wr = w >> 1, wc = w & 1;
  const long m0 = (long)blockIdx.x * 128;
  const long n0 = (long)blockIdx.y * 128;
  const int K = 1024;

  const int srow = w * 16 + (l >> 2);
  const int skof = (l & 3) * 8;
  const __bf16* gA = A + (m0 + srow) * (long)K + skof;
  const __bf16* gB = Bt + (n0 + srow) * (long)K + skof;
  const int Ao[2] = {0, 8192}, Bo[2] = {4096, 12288};
  const int lof = w * 512 + l * 8;

  async16(smem + Ao[0] + lof,        gA);
  async16(smem + Ao[0] + 2048 + lof, gA + 64 * (long)K);
  async16(smem + Bo[0] + lof,        gB);
  async16(smem + Bo[0] + 2048 + lof, gB + 64 * (long)K);
  gA += 32; gB += 32;
  __syncthreads();

  f32x4 acc[4][4] = {};

  for (int it = 0; it < 32; it++) {
    if (it < 31) {
      const int nb = (it + 1) & 1;
      async16(smem + Ao[nb] + lof,        gA);
      async16(smem + Ao[nb] + 2048 + lof, gA + 64 * (long)K);
      async16(smem + Bo[nb] + lof,        gB);
      async16(smem + Bo[nb] + 2048 + lof, gB + 64 * (long)K);
      gA += 32; gB += 32;
    }
    const __bf16* As = smem + Ao[it & 1];
    const __bf16* Bs = smem + Bo[it & 1];
    bf16x8 af[4], bfr[4];
#pragma unroll
    for (int mi = 0; mi < 4; mi++)
      af[mi] = *(const bf16x8*)&As[(wr * 64 + mi * 16 + (l & 15)) * 32 + (l >> 4) * 8];
#pragma unroll
    for (int ni = 0; ni < 4; ni++)
      bfr[ni] = *(const bf16x8*)&Bs[(wc * 64 + ni * 16 + (l & 15)) * 32 + (l >> 4) * 8];
#pragma unroll
    for (int mi = 0; mi < 4; mi++)
#pragma unroll
      for (int ni = 0; ni < 4; ni++)
        acc[mi][ni] = __builtin_amdgcn_mfma_f32_16x16x32_bf16(af[mi], bfr[ni], acc[mi][ni], 0, 0, 0);
    __syncthreads();
  }

  if (n0 < 2048) {
#pragma unroll
    for (int mi = 0; mi < 4; mi++)
#pragma unroll
      for (int ni = 0; ni < 4; ni++) {
        const long col = n0 + wc * 64 + ni * 16 + (l & 15);
#pragma unroll
        for (int r = 0; r < 4; r++) {
          const long row = m0 + wr * 64 + mi * 16 + (l >> 4) * 4 + r;
          Cqk[row * 2048 + col] = (__bf16)acc[mi][ni][r];
        }
      }
  } else {
#pragma unroll
    for (int mi = 0; mi < 4; mi++)
#pragma unroll
      for (int ni = 0; ni < 4; ni++) {
        const int c = wc * 64 + ni * 16 + (l & 15);
        const int r = wr * 64 + mi * 16 + (l >> 4) * 4;
        bf16x4 pk;
#pragma unroll
        for (int k = 0; k < 4; k++) pk[k] = (__bf16)acc[mi][ni][k];
        *(bf16x4*)&smem[c * 136 + r] = pk;
      }
    __syncthreads();
    const int b = (int)(m0 >> 11);
    const int nbase = (int)(m0 & 2047);
#pragma unroll
    for (int i = 0; i < 8; i++) {
      const int c = (t >> 4) + i * 16;
      const int r8 = (t & 15) * 8;
      const bf16x8 v = *(const bf16x8*)&smem[c * 136 + r8];
      const int vcol = (int)(n0 - 2048) + c;
      *(bf16x8*)&Vt[((long)(b * 16 + (vcol >> 6)) * 64 + (vcol & 63)) * 2048 + nbase + r8] = v;
    }
  }
}

// ---------------- out GEMM: [4096,1024] x [1024,1024]^T + bias, 128x64 tile.
__global__ __launch_bounds__(256, 2) void gemm_out(
    const __bf16* __restrict__ A, const __bf16* __restrict__ Bt,
    const void* __restrict__ bias_raw, void* __restrict__ C,
    const int* __restrict__ flagp)
{
  __shared__ __bf16 smem[12288];
  const int t = threadIdx.x;
  const int l = t & 63;
  const int w = t >> 6;
  const int wr = w >> 1, wc = w & 1;
  const long m0 = (long)blockIdx.x * 128;
  const long n0 = (long)blockIdx.y * 64;
  const int of = *flagp;
  const int K = 1024;

  const int srow = w * 16 + (l >> 2);
  const int skof = (l & 3) * 8;
  const __bf16* gA = A + (m0 + srow) * (long)K + skof;
  const __bf16* gB = Bt + (n0 + srow) * (long)K + skof;
  const int Ao[2] = {0, 6144}, Bo[2] = {4096, 10240};
  const int lof = w * 512 + l * 8;

  async16(smem + Ao[0] + lof,        gA);
  async16(smem + Ao[0] + 2048 + lof, gA + 64 * (long)K);
  async16(smem + Bo[0] + lof,        gB);
  gA += 32; gB += 32;
  __syncthreads();

  f32x4 acc[4][2] = {};

  for (int it = 0; it < 32; it++) {
    if (it < 31) {
      const int nb = (it + 1) & 1;
      async16(smem + Ao[nb] + lof,        gA);
      async16(smem + Ao[nb] + 2048 + lof, gA + 64 * (long)K);
      async16(smem + Bo[nb] + lof,        gB);
      gA += 32; gB += 32;
    }
    const __bf16* As = smem + Ao[it & 1];
    const __bf16* Bs = smem + Bo[it & 1];
    bf16x8 af[4], bfr[2];
#pragma unroll
    for (int mi = 0; mi < 4; mi++)
      af[mi] = *(const bf16x8*)&As[(wr * 64 + mi * 16 + (l & 15)) * 32 + (l >> 4) * 8];
#pragma unroll
    for (int ni = 0; ni < 2; ni++)
      bfr[ni] = *(const bf16x8*)&Bs[(wc * 32 + ni * 16 + (l & 15)) * 32 + (l >> 4) * 8];
#pragma unroll
    for (int mi = 0; mi < 4; mi++)
#pragma unroll
      for (int ni = 0; ni < 2; ni++)
        acc[mi][ni] = __builtin_amdgcn_mfma_f32_16x16x32_bf16(af[mi], bfr[ni], acc[mi][ni], 0, 0, 0);
    __syncthreads();
  }

#pragma unroll
  for (int mi = 0; mi < 4; mi++)
#pragma unroll
    for (int ni = 0; ni < 2; ni++) {
      const long col = n0 + wc * 32 + ni * 16 + (l & 15);
      const float bv = of ? ((const float*)bias_raw)[col]
                          : (float)((const __bf16*)bias_raw)[col];
#pragma unroll
      for (int r = 0; r < 4; r++) {
        const long row = m0 + wr * 64 + mi * 16 + (l >> 4) * 4 + r;
        const float val = acc[mi][ni][r] + bv;
        const long off = row * 1024 + col;
        if (of) ((float*)C)[off] = val;
        else    ((__bf16*)C)[off] = (__bf16)val;
      }
    }
}

// ---------------- flash attention, register-resident P + skewed-PV pipeline
// (T12 + T15). Wave (wi,wj): St[j in wj-half][i in wi-half] via mfma(K,Q);
// P stays in registers (bf16 packs + permlane32_swap for the half-wave j
// exchange). PV of tile t is DEFERRED to iteration t+1: V-frags are read to
// regs during iter t (LDS buffer then dead -> prefetch safe), and PV(t-1)
// issues as a pure-register MFMA cluster at the top of iter t, overlapping
// the ds_read K -> St -> softmax chain it is independent of. l_i cross-half
// combine deferred to one epilogue permlane (linear op). One barrier/tile.
#define EXP2_SCALE 0.045084439f   // (1/32) * log2(e)

__global__ __launch_bounds__(256, 4) void attn_kernel(
    const __bf16* __restrict__ qk, const __bf16* __restrict__ Vt,
    __bf16* __restrict__ O)
{
  __shared__ __bf16 smem[16384];   // K0@0 V0@4096 K1@8192 V1@12288 (elements)
  const int t = threadIdx.x;
  const int l = t & 63;
  const int w = t >> 6;
  const int wi = w & 1, wj = w >> 1;
  const int hl = l >> 5;
  const int i7 = l & 7;
  // XCD swizzle: same bh => same (linear % 8) => same XCD L2.
  const int L = blockIdx.y * 32 + blockIdx.x;
  const int bh = (L & 7) * 4 + ((L >> 3) & 3);
  const int qt = L >> 5;
  const int b = bh >> 4, head = bh & 15;
  const long q_row0 = (long)b * 2048 + qt * 64;

  const int srow = w * 8 + (l >> 3);
  const int sdof = ((l & 7) ^ (l >> 3)) * 8;
  const int lof = w * 512 + l * 8;

  // prolog: tile 0 K/V staging
  const __bf16* gK = qk + ((long)b * 2048 + srow) * 2048 + 1024 + head * 64 + sdof;
  const __bf16* gV = Vt + ((long)bh * 64 + srow) * 2048 + sdof;
  async16(smem + lof,        gK);
  async16(smem + 2048 + lof, gK + 32 * 2048);
  async16(smem + 4096 + lof, gV);
  async16(smem + 6144 + lof, gV + 32 * 2048);
  gK += (long)64 * 2048;
  gV += 64;

  // Q fragments direct from global (rows wi*32+(l&31), k-elems hl*8 per chunk)
  bf16x8 qf[4];
  {
    const __bf16* gQ = qk + (q_row0 + wi * 32 + (l & 31)) * 2048 + head * 64 + hl * 8;
#pragma unroll
    for (int kc = 0; kc < 4; kc++)
      qf[kc] = *(const bf16x8*)(gQ + kc * 16);
  }

  f32x16 accA = {0,0,0,0,0,0,0,0,0,0,0,0,0,0,0,0};  // d 0..31
  f32x16 accB = {0,0,0,0,0,0,0,0,0,0,0,0,0,0,0,0};  // d 32..63
  float l_i = 0.0f;                                  // own j-half only

  // previous-tile state (P frags + V frags), consumed by the skewed PV
  bf16x8 pa0 = {}, pa1 = {};
  bf16x8 pvA0 = {}, pvA1 = {}, pvB0 = {}, pvB1 = {};

  const int krow = (wj * 32 + (l & 31)) * 64;
  const int vg = wj * 4;

  for (int it = 0; it < 32; it++) {
    __syncthreads();               // drains prefetch for cur (all waves)
    const __bf16* Ks = smem + (it & 1) * 8192;
    const __bf16* Vs = Ks + 4096;

    // issue K ds_reads first
    bf16x8 ak[4];
#pragma unroll
    for (int kc = 0; kc < 4; kc++)
      ak[kc] = *(const bf16x8*)&Ks[krow + (((kc * 2 + hl) ^ i7) * 8)];

    // prefetch next K/V tile into the dead buffer (t-1's data fully consumed)
    if (it < 31) {
      const int nb = ((it + 1) & 1) * 8192;
      async16(smem + nb + lof,        gK);
      async16(smem + nb + 2048 + lof, gK + 32 * 2048);
      async16(smem + nb + 4096 + lof, gV);
      async16(smem + nb + 6144 + lof, gV + 32 * 2048);
      gK += (long)64 * 2048;
      gV += 64;
    }

    __builtin_amdgcn_s_setprio(1);
    // skewed PV(t-1): pure-register MFMAs, independent of the K-read chain
    if (it > 0) {
      accA = __builtin_amdgcn_mfma_f32_32x32x16_bf16(pa0, pvA0, accA, 0, 0, 0);
      accB = __builtin_amdgcn_mfma_f32_32x32x16_bf16(pa0, pvB0, accB, 0, 0, 0);
      accA = __builtin_amdgcn_mfma_f32_32x32x16_bf16(pa1, pvA1, accA, 0, 0, 0);
      accB = __builtin_amdgcn_mfma_f32_32x32x16_bf16(pa1, pvB1, accB, 0, 0, 0);
    }
    // St[j in wj-half][i in wi-half]
    f32x16 st = {0,0,0,0,0,0,0,0,0,0,0,0,0,0,0,0};
#pragma unroll
    for (int kc = 0; kc < 4; kc++)
      st = __builtin_amdgcn_mfma_f32_32x32x16_bf16(ak[kc], qf[kc], st, 0, 0, 0);
    __builtin_amdgcn_s_setprio(0);

    // V frags of CURRENT tile -> regs (used by next iteration's PV);
    // LDS latency hides under the softmax VALU chain below.
    pvA0 = *(const bf16x8*)&Vs[((l & 31)) * 64      + (((vg + hl) ^ i7) * 8)];
    pvB0 = *(const bf16x8*)&Vs[(32 + (l & 31)) * 64 + (((vg + hl) ^ i7) * 8)];
    pvA1 = *(const bf16x8*)&Vs[((l & 31)) * 64      + (((vg + 2 + hl) ^ i7) * 8)];
    pvB1 = *(const bf16x8*)&Vs[(32 + (l & 31)) * 64 + (((vg + 2 + hl) ^ i7) * 8)];

    // exp + row-sum (lane owns 16 scores of query i = wi*32+(l&31); regs
    // cover j_off = (r&3)+8*(r>>2)+4*hl within this wave's wj-half)
    float rs = 0.0f;
#pragma unroll
    for (int r = 0; r < 16; r++) {
      const float p = exp2f(st[r] * EXP2_SCALE);
      st[r] = p;
      rs += p;
    }
    l_i += rs;                     // own half; cross-half combine in epilogue

    // in-register P -> bf16 A-fragments for this wave's 32 j's (2 chunks).
    unsigned int a0 = pack2(st[0],  st[1]),  b0 = pack2(st[4],  st[5]);
    unsigned int c0 = pack2(st[2],  st[3]),  d0 = pack2(st[6],  st[7]);
    unsigned int a1 = pack2(st[8],  st[9]),  b1 = pack2(st[12], st[13]);
    unsigned int c1 = pack2(st[10], st[11]), d1 = pack2(st[14], st[15]);
    plswap(a0, b0);
    plswap(c0, d0);
    plswap(a1, b1);
    plswap(c1, d1);
    const i32x4 f0 = {(int)a0, (int)c0, (int)b0, (int)d0};
    const i32x4 f1 = {(int)a1, (int)c1, (int)b1, (int)d1};
    pa0 = __builtin_bit_cast(bf16x8, f0);
    pa1 = __builtin_bit_cast(bf16x8, f1);
  }

  // drain: PV of the last tile (register-only)
  accA = __builtin_amdgcn_mfma_f32_32x32x16_bf16(pa0, pvA0, accA, 0, 0, 0);
  accB = __builtin_amdgcn_mfma_f32_32x32x16_bf16(pa0, pvB0, accB, 0, 0, 0);
  accA = __builtin_amdgcn_mfma_f32_32x32x16_bf16(pa1, pvA1, accA, 0, 0, 0);
  accB = __builtin_amdgcn_mfma_f32_32x32x16_bf16(pa1, pvB1, accB, 0, 0, 0);

  // combine l_i across the two half-waves (one permlane, deferred from loop)
  {
    unsigned int a = __builtin_bit_cast(unsigned int, l_i), bswp = a;
    plswap(a, bswp);
    l_i = __builtin_bit_cast(float, a) + __builtin_bit_cast(float, bswp);
  }

  // epilogue: combine partial O across the wj pair + l_i across wj, store.
  __syncthreads();                       // all tile reads done; LDS reusable
  float* xbf = (float*)smem;             // 4 waves x 1024 f32 = 16KB
  float* lb  = (float*)(smem + 8192);    // 128 floats (bytes 16384..16896)
#pragma unroll
  for (int r = 0; r < 16; r++)           // publish the OTHER d-half partial
    xbf[w * 1024 + r * 64 + l] = wj ? accA[r] : accB[r];
  if (l < 32) lb[w * 32 + l] = l_i;
  __syncthreads();
  const int pw = 2 * (1 - wj) + wi;      // partner wave (same wi, other wj)
#pragma unroll
  for (int r = 0; r < 16; r++) {
    const int iloc = (r & 3) + 8 * (r >> 2) + 4 * hl;
    const float lt = lb[wi * 32 + iloc] + lb[(wi + 2) * 32 + iloc];
    const float own = wj ? accB[r] : accA[r];
    const float o = own + xbf[pw * 1024 + r * 64 + l];
    const long row = q_row0 + wi * 32 + iloc;
    const long col = (long)head * 64 + wj * 32 + (l & 31);
    O[row * 1024 + col] = (__bf16)(o / lt);
  }
}

extern "C" void kernel_launch(void* const* d_in, const int* in_sizes, int n_in,
                              void* d_out, int out_size, void* d_ws, size_t ws_size,
                              hipStream_t stream) {
  const void* x    = d_in[0];
  const void* Wqkv = d_in[1];
  const void* Wout = d_in[2];
  const void* bout = d_in[3];

  char* ws = (char*)d_ws;
  int*    flagp = (int*)ws;
  __bf16* xb    = (__bf16*)(ws + 4096);                      // 8 MB (dead after gemm_qkv)
  __bf16* Obuf  = xb;                                        // alias
  __bf16* WqkvT = (__bf16*)(ws + 4096 +  8388608);           // 6 MB
  __bf16* WoutT = (__bf16*)(ws + 4096 + 14680064);           // 2 MB
  __bf16* qkbuf = (__bf16*)(ws + 4096 + 16777216);           // 16 MB
  __bf16* VtBuf = (__bf16*)(ws + 4096 + 33554432);           // 8 MB

  hipLaunchKernelGGL(prep, dim3(3072), dim3(256), 0, stream,
                     x, Wqkv, Wout, xb, WqkvT, WoutT, flagp);
  hipLaunchKernelGGL(gemm_qkv, dim3(32, 24), dim3(256), 0, stream,
                     xb, WqkvT, qkbuf, VtBuf);
  hipLaunchKernelGGL(attn_kernel, dim3(32, 32), dim3(256), 0, stream,
                     qkbuf, VtBuf, Obuf);
  hipLaunchKernelGGL(gemm_out, dim3(32, 16), dim3(256), 0, stream,
                     Obuf, WoutT, bout, d_out, flagp);
}

// Round 4
// 192.277 us; speedup vs baseline: 1.0733x; 1.0405x over previous
//
#include <hip/hip_runtime.h>

typedef __bf16 bf16x8 __attribute__((ext_vector_type(8)));
typedef __bf16 bf16x4 __attribute__((ext_vector_type(4)));
typedef __bf16 bf16x2 __attribute__((ext_vector_type(2)));
typedef float f32x4 __attribute__((ext_vector_type(4)));
typedef float f32x16 __attribute__((ext_vector_type(16)));
typedef int i32x4 __attribute__((ext_vector_type(4)));
typedef unsigned int u32x2 __attribute__((ext_vector_type(2)));

__device__ __forceinline__ void async16(void* lds, const void* g) {
  __builtin_amdgcn_global_load_lds(
      (__attribute__((address_space(1))) unsigned int*)(g),
      (__attribute__((address_space(3))) unsigned int*)(lds), 16, 0, 0);
}

__device__ __forceinline__ unsigned int pack2(float a, float b) {
  bf16x2 t;
  t[0] = (__bf16)a;
  t[1] = (__bf16)b;
  return __builtin_bit_cast(unsigned int, t);
}

// raw v_exp_f32 (2^x): skips ocml's denormal-guard expansion. Scores are
// O(10) in magnitude -> no subnormal range issues.
__device__ __forceinline__ float fexp2(float x) {
#if __has_builtin(__builtin_amdgcn_exp2f)
  return __builtin_amdgcn_exp2f(x);
#else
  return exp2f(x);
#endif
}

// lane[i] <-> lane[i+32] half-wave exchange: d.hi <-> s.lo.
__device__ __forceinline__ void plswap(unsigned int& d, unsigned int& s) {
#if __has_builtin(__builtin_amdgcn_permlane32_swap)
  u32x2 r = __builtin_amdgcn_permlane32_swap(d, s, false, false);
  d = r[0];
  s = r[1];
#else
  asm("v_permlane32_swap_b32 %0, %1" : "+v"(d), "+v"(s));
#endif
}

// Per-block dtype self-detect on a 2048-u16 window.
__device__ __forceinline__ int detect_block(const unsigned short* win, int* cnt_sh) {
  if (threadIdx.x == 0) *cnt_sh = 0;
  __syncthreads();
  int c = 0;
#pragma unroll
  for (int j = 0; j < 8; j++) {
    const unsigned short u = win[threadIdx.x * 8 + j];
    if (((u >> 7) & 0xFF) >= 0xC0) c++;
  }
  if (c) atomicAdd(cnt_sh, c);
  __syncthreads();
  return (*cnt_sh >= 64) ? 1 : 0;
}

// ---------------- prep: x->bf16 cvt (blocks 0..2047) + Wqkv transpose
// (2048..2815) + Wout transpose (2816..3071), all self-detecting dtype.
__global__ __launch_bounds__(256) void prep(
    const void* __restrict__ x, const void* __restrict__ Wqkv,
    const void* __restrict__ Wout, __bf16* __restrict__ xb,
    __bf16* __restrict__ WqkvT, __bf16* __restrict__ WoutT,
    int* __restrict__ flagp)
{
  __shared__ __bf16 tile[64 * 65];
  __shared__ int cnt;
  const int bx = blockIdx.x;
  const int t = threadIdx.x;

  if (bx < 2048) {
    const long base = (long)bx * 2048;
    const int f = detect_block((const unsigned short*)x + base, &cnt);
    if (bx == 0 && t == 0) *flagp = f;
    const long i = base + t * 8;
    if (f) {
      const float* s = (const float*)x;
#pragma unroll
      for (int j = 0; j < 8; j++) xb[i + j] = (__bf16)s[i + j];
    } else {
      *(bf16x8*)&xb[i] = *(const bf16x8*)((const __bf16*)x + i);
    }
    return;
  }

  const void* in;  __bf16* out;  int R = 1024, C, tcx, tr;
  if (bx < 2816) {
    const int idx = bx - 2048;
    in = Wqkv; out = WqkvT; C = 3072; tcx = (idx % 48) * 64; tr = (idx / 48) * 64;
  } else {
    const int idx = bx - 2816;
    in = Wout; out = WoutT; C = 1024; tcx = (idx % 16) * 64; tr = (idx / 16) * 64;
  }
  const int f = detect_block((const unsigned short*)in + (long)tr * C + tcx, &cnt);
#pragma unroll
  for (int i = 0; i < 16; i++) {
    const int idx = t + 256 * i;
    const int r = idx >> 6, c = idx & 63;
    const long g = (long)(tr + r) * C + tcx + c;
    tile[r * 65 + c] = f ? (__bf16)((const float*)in)[g] : ((const __bf16*)in)[g];
  }
  __syncthreads();
#pragma unroll
  for (int i = 0; i < 16; i++) {
    const int idx = t + 256 * i;
    const int r = idx >> 6, c = idx & 63;
    out[(long)(tcx + r) * R + tr + c] = tile[c * 65 + r];
  }
}

// ---------------- qkv GEMM: [4096,1024] x [1024,3072]^T, prefetch-pipelined.
// Q,K -> qk (stride 2048); V -> Vt[bh*64+d][2048] via padded-LDS transpose.
// XCD-bijective swizzle (768 = 8*96): each XCD owns 3 n-columns x all m ->
// each B-panel cached in exactly one XCD L2.
__global__ __launch_bounds__(256, 3) void gemm_qkv(
    const __bf16* __restrict__ A, const __bf16* __restrict__ Bt,
    __bf16* __restrict__ Cqk, __bf16* __restrict__ Vt)
{
  __shared__ __bf16 smem[17408];
  const int t = threadIdx.x;
  const int l = t & 63;
  const int w = t >> 6;
  const int wr = w >> 1, wc = w & 1;
  const int lid = blockIdx.y * 32 + blockIdx.x;
  const int s = (lid & 7) * 96 + (lid >> 3);
  const long m0 = (long)(s & 31) * 128;
  const long n0 = (long)(s >> 5) * 128;
  const int K = 1024;

  const int srow = w * 16 + (l >> 2);
  const int skof = (l & 3) * 8;
  const __bf16* gA = A + (m0 + srow) * (long)K + skof;
  const __bf16* gB = Bt + (n0 + srow) * (long)K + skof;
  const int Ao[2] = {0, 8192}, Bo[2] = {4096, 12288};
  const int lof = w * 512 + l * 8;

  async16(smem + Ao[0] + lof,        gA);
  async16(smem + Ao[0] + 2048 + lof, gA + 64 * (long)K);
  async16(smem + Bo[0] + lof,        gB);
  async16(smem + Bo[0] + 2048 + lof, gB + 64 * (long)K);
  gA += 32; gB += 32;
  __syncthreads();

  f32x4 acc[4][4] = {};

  for (int it = 0; it < 32; it++) {
    if (it < 31) {
      const int nb = (it + 1) & 1;
      async16(smem + Ao[nb] + lof,        gA);
      async16(smem + Ao[nb] + 2048 + lof, gA + 64 * (long)K);
      async16(smem + Bo[nb] + lof,        gB);
      async16(smem + Bo[nb] + 2048 + lof, gB + 64 * (long)K);
      gA += 32; gB += 32;
    }
    const __bf16* As = smem + Ao[it & 1];
    const __bf16* Bs = smem + Bo[it & 1];
    bf16x8 af[4], bfr[4];
#pragma unroll
    for (int mi = 0; mi < 4; mi++)
      af[mi] = *(const bf16x8*)&As[(wr * 64 + mi * 16 + (l & 15)) * 32 + (l >> 4) * 8];
#pragma unroll
    for (int ni = 0; ni < 4; ni++)
      bfr[ni] = *(const bf16x8*)&Bs[(wc * 64 + ni * 16 + (l & 15)) * 32 + (l >> 4) * 8];
#pragma unroll
    for (int mi = 0; mi < 4; mi++)
#pragma unroll
      for (int ni = 0; ni < 4; ni++)
        acc[mi][ni] = __builtin_amdgcn_mfma_f32_16x16x32_bf16(af[mi], bfr[ni], acc[mi][ni], 0, 0, 0);
    __syncthreads();
  }

  if (n0 < 2048) {
#pragma unroll
    for (int mi = 0; mi < 4; mi++)
#pragma unroll
      for (int ni = 0; ni < 4; ni++) {
        const long col = n0 + wc * 64 + ni * 16 + (l & 15);
#pragma unroll
        for (int r = 0; r < 4; r++) {
          const long row = m0 + wr * 64 + mi * 16 + (l >> 4) * 4 + r;
          Cqk[row * 2048 + col] = (__bf16)acc[mi][ni][r];
        }
      }
  } else {
#pragma unroll
    for (int mi = 0; mi < 4; mi++)
#pragma unroll
      for (int ni = 0; ni < 4; ni++) {
        const int c = wc * 64 + ni * 16 + (l & 15);
        const int r = wr * 64 + mi * 16 + (l >> 4) * 4;
        bf16x4 pk;
#pragma unroll
        for (int k = 0; k < 4; k++) pk[k] = (__bf16)acc[mi][ni][k];
        *(bf16x4*)&smem[c * 136 + r] = pk;
      }
    __syncthreads();
    const int b = (int)(m0 >> 11);
    const int nbase = (int)(m0 & 2047);
#pragma unroll
    for (int i = 0; i < 8; i++) {
      const int c = (t >> 4) + i * 16;
      const int r8 = (t & 15) * 8;
      const bf16x8 v = *(const bf16x8*)&smem[c * 136 + r8];
      const int vcol = (int)(n0 - 2048) + c;
      *(bf16x8*)&Vt[((long)(b * 16 + (vcol >> 6)) * 64 + (vcol & 63)) * 2048 + nbase + r8] = v;
    }
  }
}

// ---------------- out GEMM: [4096,1024] x [1024,1024]^T + bias, 128x64 tile.
// XCD-bijective swizzle (512 = 8*64): each XCD owns 2 n-columns x all m.
__global__ __launch_bounds__(256, 2) void gemm_out(
    const __bf16* __restrict__ A, const __bf16* __restrict__ Bt,
    const void* __restrict__ bias_raw, void* __restrict__ C,
    const int* __restrict__ flagp)
{
  __shared__ __bf16 smem[12288];
  const int t = threadIdx.x;
  const int l = t & 63;
  const int w = t >> 6;
  const int wr = w >> 1, wc = w & 1;
  const int lid = blockIdx.y * 32 + blockIdx.x;
  const int s = (lid & 7) * 64 + (lid >> 3);
  const long m0 = (long)(s & 31) * 128;
  const long n0 = (long)(s >> 5) * 64;
  const int of = *flagp;
  const int K = 1024;

  const int srow = w * 16 + (l >> 2);
  const int skof = (l & 3) * 8;
  const __bf16* gA = A + (m0 + srow) * (long)K + skof;
  const __bf16* gB = Bt + (n0 + srow) * (long)K + skof;
  const int Ao[2] = {0, 6144}, Bo[2] = {4096, 10240};
  const int lof = w * 512 + l * 8;

  async16(smem + Ao[0] + lof,        gA);
  async16(smem + Ao[0] + 2048 + lof, gA + 64 * (long)K);
  async16(smem + Bo[0] + lof,        gB);
  gA += 32; gB += 32;
  __syncthreads();

  f32x4 acc[4][2] = {};

  for (int it = 0; it < 32; it++) {
    if (it < 31) {
      const int nb = (it + 1) & 1;
      async16(smem + Ao[nb] + lof,        gA);
      async16(smem + Ao[nb] + 2048 + lof, gA + 64 * (long)K);
      async16(smem + Bo[nb] + lof,        gB);
      gA += 32; gB += 32;
    }
    const __bf16* As = smem + Ao[it & 1];
    const __bf16* Bs = smem + Bo[it & 1];
    bf16x8 af[4], bfr[2];
#pragma unroll
    for (int mi = 0; mi < 4; mi++)
      af[mi] = *(const bf16x8*)&As[(wr * 64 + mi * 16 + (l & 15)) * 32 + (l >> 4) * 8];
#pragma unroll
    for (int ni = 0; ni < 2; ni++)
      bfr[ni] = *(const bf16x8*)&Bs[(wc * 32 + ni * 16 + (l & 15)) * 32 + (l >> 4) * 8];
#pragma unroll
    for (int mi = 0; mi < 4; mi++)
#pragma unroll
      for (int ni = 0; ni < 2; ni++)
        acc[mi][ni] = __builtin_amdgcn_mfma_f32_16x16x32_bf16(af[mi], bfr[ni], acc[mi][ni], 0, 0, 0);
    __syncthreads();
  }

#pragma unroll
  for (int mi = 0; mi < 4; mi++)
#pragma unroll
    for (int ni = 0; ni < 2; ni++) {
      const long col = n0 + wc * 32 + ni * 16 + (l & 15);
      const float bv = of ? ((const float*)bias_raw)[col]
                          : (float)((const __bf16*)bias_raw)[col];
#pragma unroll
      for (int r = 0; r < 4; r++) {
        const long row = m0 + wr * 64 + mi * 16 + (l >> 4) * 4 + r;
        const float val = acc[mi][ni][r] + bv;
        const long off = row * 1024 + col;
        if (of) ((float*)C)[off] = val;
        else    ((__bf16*)C)[off] = (__bf16)val;
      }
    }
}

// ---------------- flash attention, register-resident P + skewed-PV pipeline
// (T12 + T15). Wave (wi,wj): St[j in wj-half][i in wi-half] via mfma(K,Q);
// P stays in registers (bf16 packs + permlane32_swap for the half-wave j
// exchange). PV of tile t is DEFERRED to iteration t+1 as a pure-register
// MFMA cluster overlapping the ds_read K -> St -> softmax chain. VALU diet
// (R4): raw v_exp_f32 via builtin (skips ocml denorm guards), hoisted MFMA
// zero C-in (no per-iter re-zeroing), split rs accumulators.
#define EXP2_SCALE 0.045084439f   // (1/32) * log2(e)

__global__ __launch_bounds__(256, 4) void attn_kernel(
    const __bf16* __restrict__ qk, const __bf16* __restrict__ Vt,
    __bf16* __restrict__ O)
{
  __shared__ __bf16 smem[16384];   // K0@0 V0@4096 K1@8192 V1@12288 (elements)
  const int t = threadIdx.x;
  const int l = t & 63;
  const int w = t >> 6;
  const int wi = w & 1, wj = w >> 1;
  const int hl = l >> 5;
  const int i7 = l & 7;
  // XCD swizzle: same bh => same (linear % 8) => same XCD L2.
  const int L = blockIdx.y * 32 + blockIdx.x;
  const int bh = (L & 7) * 4 + ((L >> 3) & 3);
  const int qt = L >> 5;
  const int b = bh >> 4, head = bh & 15;
  const long q_row0 = (long)b * 2048 + qt * 64;

  const int srow = w * 8 + (l >> 3);
  const int sdof = ((l & 7) ^ (l >> 3)) * 8;
  const int lof = w * 512 + l * 8;

  // prolog: tile 0 K/V staging
  const __bf16* gK = qk + ((long)b * 2048 + srow) * 2048 + 1024 + head * 64 + sdof;
  const __bf16* gV = Vt + ((long)bh * 64 + srow) * 2048 + sdof;
  async16(smem + lof,        gK);
  async16(smem + 2048 + lof, gK + 32 * 2048);
  async16(smem + 4096 + lof, gV);
  async16(smem + 6144 + lof, gV + 32 * 2048);
  gK += (long)64 * 2048;
  gV += 64;

  // Q fragments direct from global (rows wi*32+(l&31), k-elems hl*8 per chunk)
  bf16x8 qf[4];
  {
    const __bf16* gQ = qk + (q_row0 + wi * 32 + (l & 31)) * 2048 + head * 64 + hl * 8;
#pragma unroll
    for (int kc = 0; kc < 4; kc++)
      qf[kc] = *(const bf16x8*)(gQ + kc * 16);
  }

  f32x16 accA = {0,0,0,0,0,0,0,0,0,0,0,0,0,0,0,0};  // d 0..31
  f32x16 accB = {0,0,0,0,0,0,0,0,0,0,0,0,0,0,0,0};  // d 32..63
  const f32x16 fz = {0,0,0,0,0,0,0,0,0,0,0,0,0,0,0,0};  // hoisted MFMA C-in
  float l_i = 0.0f;                                  // own j-half only

  // previous-tile state (P frags + V frags), consumed by the skewed PV
  bf16x8 pa0 = {}, pa1 = {};
  bf16x8 pvA0 = {}, pvA1 = {}, pvB0 = {}, pvB1 = {};

  const int krow = (wj * 32 + (l & 31)) * 64;
  const int vg = wj * 4;

  for (int it = 0; it < 32; it++) {
    __syncthreads();               // drains prefetch for cur (all waves)
    const __bf16* Ks = smem + (it & 1) * 8192;
    const __bf16* Vs = Ks + 4096;

    // issue K ds_reads first
    bf16x8 ak[4];
#pragma unroll
    for (int kc = 0; kc < 4; kc++)
      ak[kc] = *(const bf16x8*)&Ks[krow + (((kc * 2 + hl) ^ i7) * 8)];

    // prefetch next K/V tile into the dead buffer (t-1's data fully consumed)
    if (it < 31) {
      const int nb = ((it + 1) & 1) * 8192;
      async16(smem + nb + lof,        gK);
      async16(smem + nb + 2048 + lof, gK + 32 * 2048);
      async16(smem + nb + 4096 + lof, gV);
      async16(smem + nb + 6144 + lof, gV + 32 * 2048);
      gK += (long)64 * 2048;
      gV += 64;
    }

    __builtin_amdgcn_s_setprio(1);
    // skewed PV(t-1): pure-register MFMAs, independent of the K-read chain
    if (it > 0) {
      accA = __builtin_amdgcn_mfma_f32_32x32x16_bf16(pa0, pvA0, accA, 0, 0, 0);
      accB = __builtin_amdgcn_mfma_f32_32x32x16_bf16(pa0, pvB0, accB, 0, 0, 0);
      accA = __builtin_amdgcn_mfma_f32_32x32x16_bf16(pa1, pvA1, accA, 0, 0, 0);
      accB = __builtin_amdgcn_mfma_f32_32x32x16_bf16(pa1, pvB1, accB, 0, 0, 0);
    }
    // St[j in wj-half][i in wi-half]; C-in = hoisted zero (no per-iter movs)
    f32x16 st = __builtin_amdgcn_mfma_f32_32x32x16_bf16(ak[0], qf[0], fz, 0, 0, 0);
#pragma unroll
    for (int kc = 1; kc < 4; kc++)
      st = __builtin_amdgcn_mfma_f32_32x32x16_bf16(ak[kc], qf[kc], st, 0, 0, 0);
    __builtin_amdgcn_s_setprio(0);

    // V frags of CURRENT tile -> regs (used by next iteration's PV);
    // LDS latency hides under the softmax VALU chain below.
    pvA0 = *(const bf16x8*)&Vs[((l & 31)) * 64      + (((vg + hl) ^ i7) * 8)];
    pvB0 = *(const bf16x8*)&Vs[(32 + (l & 31)) * 64 + (((vg + hl) ^ i7) * 8)];
    pvA1 = *(const bf16x8*)&Vs[((l & 31)) * 64      + (((vg + 2 + hl) ^ i7) * 8)];
    pvB1 = *(const bf16x8*)&Vs[(32 + (l & 31)) * 64 + (((vg + 2 + hl) ^ i7) * 8)];

    // exp + row-sum via raw v_exp_f32 (lane owns 16 scores of query i)
    float rs0 = 0.0f, rs1 = 0.0f;
#pragma unroll
    for (int r = 0; r < 16; r += 2) {
      const float p0 = fexp2(st[r] * EXP2_SCALE);
      const float p1 = fexp2(st[r + 1] * EXP2_SCALE);
      st[r] = p0;
      st[r + 1] = p1;
      rs0 += p0;
      rs1 += p1;
    }
    l_i += rs0 + rs1;              // own half; cross-half combine in epilogue

    // in-register P -> bf16 A-fragments for this wave's 32 j's (2 chunks).
    unsigned int a0 = pack2(st[0],  st[1]),  b0 = pack2(st[4],  st[5]);
    unsigned int c0 = pack2(st[2],  st[3]),  d0 = pack2(st[6],  st[7]);
    unsigned int a1 = pack2(st[8],  st[9]),  b1 = pack2(st[12], st[13]);
    unsigned int c1 = pack2(st[10], st[11]), d1 = pack2(st[14], st[15]);
    plswap(a0, b0);
    plswap(c0, d0);
    plswap(a1, b1);
    plswap(c1, d1);
    const i32x4 f0 = {(int)a0, (int)c0, (int)b0, (int)d0};
    const i32x4 f1 = {(int)a1, (int)c1, (int)b1, (int)d1};
    pa0 = __builtin_bit_cast(bf16x8, f0);
    pa1 = __builtin_bit_cast(bf16x8, f1);
  }

  // drain: PV of the last tile (register-only)
  accA = __builtin_amdgcn_mfma_f32_32x32x16_bf16(pa0, pvA0, accA, 0, 0, 0);
  accB = __builtin_amdgcn_mfma_f32_32x32x16_bf16(pa0, pvB0, accB, 0, 0, 0);
  accA = __builtin_amdgcn_mfma_f32_32x32x16_bf16(pa1, pvA1, accA, 0, 0, 0);
  accB = __builtin_amdgcn_mfma_f32_32x32x16_bf16(pa1, pvB1, accB, 0, 0, 0);

  // combine l_i across the two half-waves (one permlane, deferred from loop)
  {
    unsigned int a = __builtin_bit_cast(unsigned int, l_i), bswp = a;
    plswap(a, bswp);
    l_i = __builtin_bit_cast(float, a) + __builtin_bit_cast(float, bswp);
  }

  // epilogue: combine partial O across the wj pair + l_i across wj, store.
  __syncthreads();                       // all tile reads done; LDS reusable
  float* xbf = (float*)smem;             // 4 waves x 1024 f32 = 16KB
  float* lb  = (float*)(smem + 8192);    // 128 floats (bytes 16384..16896)
#pragma unroll
  for (int r = 0; r < 16; r++)           // publish the OTHER d-half partial
    xbf[w * 1024 + r * 64 + l] = wj ? accA[r] : accB[r];
  if (l < 32) lb[w * 32 + l] = l_i;
  __syncthreads();
  const int pw = 2 * (1 - wj) + wi;      // partner wave (same wi, other wj)
#pragma unroll
  for (int r = 0; r < 16; r++) {
    const int iloc = (r & 3) + 8 * (r >> 2) + 4 * hl;
    const float lt = lb[wi * 32 + iloc] + lb[(wi + 2) * 32 + iloc];
    const float own = wj ? accB[r] : accA[r];
    const float o = own + xbf[pw * 1024 + r * 64 + l];
    const long row = q_row0 + wi * 32 + iloc;
    const long col = (long)head * 64 + wj * 32 + (l & 31);
    O[row * 1024 + col] = (__bf16)(o / lt);
  }
}

extern "C" void kernel_launch(void* const* d_in, const int* in_sizes, int n_in,
                              void* d_out, int out_size, void* d_ws, size_t ws_size,
                              hipStream_t stream) {
  const void* x    = d_in[0];
  const void* Wqkv = d_in[1];
  const void* Wout = d_in[2];
  const void* bout = d_in[3];

  char* ws = (char*)d_ws;
  int*    flagp = (int*)ws;
  __bf16* xb    = (__bf16*)(ws + 4096);                      // 8 MB (dead after gemm_qkv)
  __bf16* Obuf  = xb;                                        // alias
  __bf16* WqkvT = (__bf16*)(ws + 4096 +  8388608);           // 6 MB
  __bf16* WoutT = (__bf16*)(ws + 4096 + 14680064);           // 2 MB
  __bf16* qkbuf = (__bf16*)(ws + 4096 + 16777216);           // 16 MB
  __bf16* VtBuf = (__bf16*)(ws + 4096 + 33554432);           // 8 MB

  hipLaunchKernelGGL(prep, dim3(3072), dim3(256), 0, stream,
                     x, Wqkv, Wout, xb, WqkvT, WoutT, flagp);
  hipLaunchKernelGGL(gemm_qkv, dim3(32, 24), dim3(256), 0, stream,
                     xb, WqkvT, qkbuf, VtBuf);
  hipLaunchKernelGGL(attn_kernel, dim3(32, 32), dim3(256), 0, stream,
                     qkbuf, VtBuf, Obuf);
  hipLaunchKernelGGL(gemm_out, dim3(32, 16), dim3(256), 0, stream,
                     Obuf, WoutT, bout, d_out, flagp);
}

// Round 5
// 192.245 us; speedup vs baseline: 1.0734x; 1.0002x over previous
//
#include <hip/hip_runtime.h>

typedef __bf16 bf16x8 __attribute__((ext_vector_type(8)));
typedef __bf16 bf16x4 __attribute__((ext_vector_type(4)));
typedef __bf16 bf16x2 __attribute__((ext_vector_type(2)));
typedef float f32x4 __attribute__((ext_vector_type(4)));
typedef float f32x16 __attribute__((ext_vector_type(16)));
typedef int i32x4 __attribute__((ext_vector_type(4)));
typedef unsigned int u32x2 __attribute__((ext_vector_type(2)));

#define EXP2_SCALE 0.045084439f   // (1/32) * log2(e), folded into Q at gemm_qkv

__device__ __forceinline__ void async16(void* lds, const void* g) {
  __builtin_amdgcn_global_load_lds(
      (__attribute__((address_space(1))) unsigned int*)(g),
      (__attribute__((address_space(3))) unsigned int*)(lds), 16, 0, 0);
}

__device__ __forceinline__ unsigned int pack2(float a, float b) {
  bf16x2 t;
  t[0] = (__bf16)a;
  t[1] = (__bf16)b;
  return __builtin_bit_cast(unsigned int, t);
}

// raw v_exp_f32 (2^x): skips ocml's denormal-guard expansion.
__device__ __forceinline__ float fexp2(float x) {
#if __has_builtin(__builtin_amdgcn_exp2f)
  return __builtin_amdgcn_exp2f(x);
#else
  return exp2f(x);
#endif
}

// lane[i] <-> lane[i+32] half-wave exchange: d.hi <-> s.lo.
__device__ __forceinline__ void plswap(unsigned int& d, unsigned int& s) {
#if __has_builtin(__builtin_amdgcn_permlane32_swap)
  u32x2 r = __builtin_amdgcn_permlane32_swap(d, s, false, false);
  d = r[0];
  s = r[1];
#else
  asm("v_permlane32_swap_b32 %0, %1" : "+v"(d), "+v"(s));
#endif
}

// Per-block dtype self-detect on a 2048-u16 window.
__device__ __forceinline__ int detect_block(const unsigned short* win, int* cnt_sh) {
  if (threadIdx.x == 0) *cnt_sh = 0;
  __syncthreads();
  int c = 0;
#pragma unroll
  for (int j = 0; j < 8; j++) {
    const unsigned short u = win[threadIdx.x * 8 + j];
    if (((u >> 7) & 0xFF) >= 0xC0) c++;
  }
  if (c) atomicAdd(cnt_sh, c);
  __syncthreads();
  return (*cnt_sh >= 64) ? 1 : 0;
}

// ---------------- prep: x->bf16 cvt (blocks 0..2047, f32 path vectorized) +
// Wqkv transpose (2048..2815) + Wout transpose (2816..3071), self-detecting.
__global__ __launch_bounds__(256) void prep(
    const void* __restrict__ x, const void* __restrict__ Wqkv,
    const void* __restrict__ Wout, __bf16* __restrict__ xb,
    __bf16* __restrict__ WqkvT, __bf16* __restrict__ WoutT,
    int* __restrict__ flagp)
{
  __shared__ __bf16 tile[64 * 65];
  __shared__ int cnt;
  const int bx = blockIdx.x;
  const int t = threadIdx.x;

  if (bx < 2048) {
    const long base = (long)bx * 2048;
    const int f = detect_block((const unsigned short*)x + base, &cnt);
    if (bx == 0 && t == 0) *flagp = f;
    const long i = base + t * 8;
    if (f) {
      const f32x4* s4 = (const f32x4*)((const float*)x + i);  // 32B-aligned
      const f32x4 v0 = s4[0], v1 = s4[1];
      bf16x8 o;
#pragma unroll
      for (int j = 0; j < 4; j++) o[j] = (__bf16)v0[j];
#pragma unroll
      for (int j = 0; j < 4; j++) o[4 + j] = (__bf16)v1[j];
      *(bf16x8*)&xb[i] = o;
    } else {
      *(bf16x8*)&xb[i] = *(const bf16x8*)((const __bf16*)x + i);
    }
    return;
  }

  const void* in;  __bf16* out;  int R = 1024, C, tcx, tr;
  if (bx < 2816) {
    const int idx = bx - 2048;
    in = Wqkv; out = WqkvT; C = 3072; tcx = (idx % 48) * 64; tr = (idx / 48) * 64;
  } else {
    const int idx = bx - 2816;
    in = Wout; out = WoutT; C = 1024; tcx = (idx % 16) * 64; tr = (idx / 16) * 64;
  }
  const int f = detect_block((const unsigned short*)in + (long)tr * C + tcx, &cnt);
#pragma unroll
  for (int i = 0; i < 16; i++) {
    const int idx = t + 256 * i;
    const int r = idx >> 6, c = idx & 63;
    const long g = (long)(tr + r) * C + tcx + c;
    tile[r * 65 + c] = f ? (__bf16)((const float*)in)[g] : ((const __bf16*)in)[g];
  }
  __syncthreads();
#pragma unroll
  for (int i = 0; i < 16; i++) {
    const int idx = t + 256 * i;
    const int r = idx >> 6, c = idx & 63;
    out[(long)(tcx + r) * R + tr + c] = tile[c * 65 + r];
  }
}

// ---------------- qkv GEMM: [4096,1024] x [1024,3072]^T, prefetch-pipelined.
// Q,K -> qk (stride 2048, Q pre-scaled by EXP2_SCALE: Q cols feed only attn);
// V -> Vt[bh*64+d][2048] via padded-LDS transpose. XCD-bijective swizzle.
__global__ __launch_bounds__(256, 3) void gemm_qkv(
    const __bf16* __restrict__ A, const __bf16* __restrict__ Bt,
    __bf16* __restrict__ Cqk, __bf16* __restrict__ Vt)
{
  __shared__ __bf16 smem[17408];
  const int t = threadIdx.x;
  const int l = t & 63;
  const int w = t >> 6;
  const int wr = w >> 1, wc = w & 1;
  const int lid = blockIdx.y * 32 + blockIdx.x;
  const int s = (lid & 7) * 96 + (lid >> 3);
  const long m0 = (long)(s & 31) * 128;
  const long n0 = (long)(s >> 5) * 128;
  const int K = 1024;

  const int srow = w * 16 + (l >> 2);
  const int skof = (l & 3) * 8;
  const __bf16* gA = A + (m0 + srow) * (long)K + skof;
  const __bf16* gB = Bt + (n0 + srow) * (long)K + skof;
  const int Ao[2] = {0, 8192}, Bo[2] = {4096, 12288};
  const int lof = w * 512 + l * 8;

  async16(smem + Ao[0] + lof,        gA);
  async16(smem + Ao[0] + 2048 + lof, gA + 64 * (long)K);
  async16(smem + Bo[0] + lof,        gB);
  async16(smem + Bo[0] + 2048 + lof, gB + 64 * (long)K);
  gA += 32; gB += 32;
  __syncthreads();

  f32x4 acc[4][4] = {};

  for (int it = 0; it < 32; it++) {
    if (it < 31) {
      const int nb = (it + 1) & 1;
      async16(smem + Ao[nb] + lof,        gA);
      async16(smem + Ao[nb] + 2048 + lof, gA + 64 * (long)K);
      async16(smem + Bo[nb] + lof,        gB);
      async16(smem + Bo[nb] + 2048 + lof, gB + 64 * (long)K);
      gA += 32; gB += 32;
    }
    const __bf16* As = smem + Ao[it & 1];
    const __bf16* Bs = smem + Bo[it & 1];
    bf16x8 af[4], bfr[4];
#pragma unroll
    for (int mi = 0; mi < 4; mi++)
      af[mi] = *(const bf16x8*)&As[(wr * 64 + mi * 16 + (l & 15)) * 32 + (l >> 4) * 8];
#pragma unroll
    for (int ni = 0; ni < 4; ni++)
      bfr[ni] = *(const bf16x8*)&Bs[(wc * 64 + ni * 16 + (l & 15)) * 32 + (l >> 4) * 8];
#pragma unroll
    for (int mi = 0; mi < 4; mi++)
#pragma unroll
      for (int ni = 0; ni < 4; ni++)
        acc[mi][ni] = __builtin_amdgcn_mfma_f32_16x16x32_bf16(af[mi], bfr[ni], acc[mi][ni], 0, 0, 0);
    __syncthreads();
  }

  if (n0 < 2048) {
    const float qs = (n0 < 1024) ? EXP2_SCALE : 1.0f;  // pre-scale Q for attn
#pragma unroll
    for (int mi = 0; mi < 4; mi++)
#pragma unroll
      for (int ni = 0; ni < 4; ni++) {
        const long col = n0 + wc * 64 + ni * 16 + (l & 15);
#pragma unroll
        for (int r = 0; r < 4; r++) {
          const long row = m0 + wr * 64 + mi * 16 + (l >> 4) * 4 + r;
          Cqk[row * 2048 + col] = (__bf16)(acc[mi][ni][r] * qs);
        }
      }
  } else {
#pragma unroll
    for (int mi = 0; mi < 4; mi++)
#pragma unroll
      for (int ni = 0; ni < 4; ni++) {
        const int c = wc * 64 + ni * 16 + (l & 15);
        const int r = wr * 64 + mi * 16 + (l >> 4) * 4;
        bf16x4 pk;
#pragma unroll
        for (int k = 0; k < 4; k++) pk[k] = (__bf16)acc[mi][ni][k];
        *(bf16x4*)&smem[c * 136 + r] = pk;
      }
    __syncthreads();
    const int b = (int)(m0 >> 11);
    const int nbase = (int)(m0 & 2047);
#pragma unroll
    for (int i = 0; i < 8; i++) {
      const int c = (t >> 4) + i * 16;
      const int r8 = (t & 15) * 8;
      const bf16x8 v = *(const bf16x8*)&smem[c * 136 + r8];
      const int vcol = (int)(n0 - 2048) + c;
      *(bf16x8*)&Vt[((long)(b * 16 + (vcol >> 6)) * 64 + (vcol & 63)) * 2048 + nbase + r8] = v;
    }
  }
}

// ---------------- out GEMM: [4096,1024] x [1024,1024]^T + bias, 128x64 tile.
// XCD-bijective swizzle (512 = 8*64).
__global__ __launch_bounds__(256, 2) void gemm_out(
    const __bf16* __restrict__ A, const __bf16* __restrict__ Bt,
    const void* __restrict__ bias_raw, void* __restrict__ C,
    const int* __restrict__ flagp)
{
  __shared__ __bf16 smem[12288];
  const int t = threadIdx.x;
  const int l = t & 63;
  const int w = t >> 6;
  const int wr = w >> 1, wc = w & 1;
  const int lid = blockIdx.y * 32 + blockIdx.x;
  const int s = (lid & 7) * 64 + (lid >> 3);
  const long m0 = (long)(s & 31) * 128;
  const long n0 = (long)(s >> 5) * 64;
  const int of = *flagp;
  const int K = 1024;

  const int srow = w * 16 + (l >> 2);
  const int skof = (l & 3) * 8;
  const __bf16* gA = A + (m0 + srow) * (long)K + skof;
  const __bf16* gB = Bt + (n0 + srow) * (long)K + skof;
  const int Ao[2] = {0, 6144}, Bo[2] = {4096, 10240};
  const int lof = w * 512 + l * 8;

  async16(smem + Ao[0] + lof,        gA);
  async16(smem + Ao[0] + 2048 + lof, gA + 64 * (long)K);
  async16(smem + Bo[0] + lof,        gB);
  gA += 32; gB += 32;
  __syncthreads();

  f32x4 acc[4][2] = {};

  for (int it = 0; it < 32; it++) {
    if (it < 31) {
      const int nb = (it + 1) & 1;
      async16(smem + Ao[nb] + lof,        gA);
      async16(smem + Ao[nb] + 2048 + lof, gA + 64 * (long)K);
      async16(smem + Bo[nb] + lof,        gB);
      gA += 32; gB += 32;
    }
    const __bf16* As = smem + Ao[it & 1];
    const __bf16* Bs = smem + Bo[it & 1];
    bf16x8 af[4], bfr[2];
#pragma unroll
    for (int mi = 0; mi < 4; mi++)
      af[mi] = *(const bf16x8*)&As[(wr * 64 + mi * 16 + (l & 15)) * 32 + (l >> 4) * 8];
#pragma unroll
    for (int ni = 0; ni < 2; ni++)
      bfr[ni] = *(const bf16x8*)&Bs[(wc * 32 + ni * 16 + (l & 15)) * 32 + (l >> 4) * 8];
#pragma unroll
    for (int mi = 0; mi < 4; mi++)
#pragma unroll
      for (int ni = 0; ni < 2; ni++)
        acc[mi][ni] = __builtin_amdgcn_mfma_f32_16x16x32_bf16(af[mi], bfr[ni], acc[mi][ni], 0, 0, 0);
    __syncthreads();
  }

#pragma unroll
  for (int mi = 0; mi < 4; mi++)
#pragma unroll
    for (int ni = 0; ni < 2; ni++) {
      const long col = n0 + wc * 32 + ni * 16 + (l & 15);
      const float bv = of ? ((const float*)bias_raw)[col]
                          : (float)((const __bf16*)bias_raw)[col];
#pragma unroll
      for (int r = 0; r < 4; r++) {
        const long row = m0 + wr * 64 + mi * 16 + (l >> 4) * 4 + r;
        const float val = acc[mi][ni][r] + bv;
        const long off = row * 1024 + col;
        if (of) ((float*)C)[off] = val;
        else    ((__bf16*)C)[off] = (__bf16)val;
      }
    }
}

// ---------------- flash attention, register-resident P + skewed-PV pipeline
// (T12 + T15). Q pre-scaled by EXP2_SCALE upstream -> exp2 directly on St.
// Row-sum l_i computed by ones-column MFMA in the skewed PV cluster (constant
// B is fragment-layout-proof): removes the 16-add VALU chain entirely.
__global__ __launch_bounds__(256, 4) void attn_kernel(
    const __bf16* __restrict__ qk, const __bf16* __restrict__ Vt,
    __bf16* __restrict__ O)
{
  __shared__ __bf16 smem[16384];   // K0@0 V0@4096 K1@8192 V1@12288 (elements)
  const int t = threadIdx.x;
  const int l = t & 63;
  const int w = t >> 6;
  const int wi = w & 1, wj = w >> 1;
  const int hl = l >> 5;
  const int i7 = l & 7;
  // XCD swizzle: same bh => same (linear % 8) => same XCD L2.
  const int L = blockIdx.y * 32 + blockIdx.x;
  const int bh = (L & 7) * 4 + ((L >> 3) & 3);
  const int qt = L >> 5;
  const int b = bh >> 4, head = bh & 15;
  const long q_row0 = (long)b * 2048 + qt * 64;

  const int srow = w * 8 + (l >> 3);
  const int sdof = ((l & 7) ^ (l >> 3)) * 8;
  const int lof = w * 512 + l * 8;

  // prolog: tile 0 K/V staging
  const __bf16* gK = qk + ((long)b * 2048 + srow) * 2048 + 1024 + head * 64 + sdof;
  const __bf16* gV = Vt + ((long)bh * 64 + srow) * 2048 + sdof;
  async16(smem + lof,        gK);
  async16(smem + 2048 + lof, gK + 32 * 2048);
  async16(smem + 4096 + lof, gV);
  async16(smem + 6144 + lof, gV + 32 * 2048);
  gK += (long)64 * 2048;
  gV += 64;

  // Q fragments direct from global (rows wi*32+(l&31), k-elems hl*8 per chunk)
  bf16x8 qf[4];
  {
    const __bf16* gQ = qk + (q_row0 + wi * 32 + (l & 31)) * 2048 + head * 64 + hl * 8;
#pragma unroll
    for (int kc = 0; kc < 4; kc++)
      qf[kc] = *(const bf16x8*)(gQ + kc * 16);
  }

  // ones B-fragment for the row-sum MFMA
  bf16x8 onesb;
#pragma unroll
  for (int j = 0; j < 8; j++) onesb[j] = (__bf16)1.0f;

  f32x16 accA = {0,0,0,0,0,0,0,0,0,0,0,0,0,0,0,0};  // d 0..31
  f32x16 accB = {0,0,0,0,0,0,0,0,0,0,0,0,0,0,0,0};  // d 32..63
  f32x16 lsum = {0,0,0,0,0,0,0,0,0,0,0,0,0,0,0,0};  // row-sums (replicated)
  const f32x16 fz = {0,0,0,0,0,0,0,0,0,0,0,0,0,0,0,0};  // hoisted MFMA C-in

  // previous-tile state (P frags + V frags), consumed by the skewed PV
  bf16x8 pa0 = {}, pa1 = {};
  bf16x8 pvA0 = {}, pvA1 = {}, pvB0 = {}, pvB1 = {};

  const int krow = (wj * 32 + (l & 31)) * 64;
  const int vg = wj * 4;

  for (int it = 0; it < 32; it++) {
    __syncthreads();               // drains prefetch for cur (all waves)
    const __bf16* Ks = smem + (it & 1) * 8192;
    const __bf16* Vs = Ks + 4096;

    // issue K ds_reads first
    bf16x8 ak[4];
#pragma unroll
    for (int kc = 0; kc < 4; kc++)
      ak[kc] = *(const bf16x8*)&Ks[krow + (((kc * 2 + hl) ^ i7) * 8)];

    // prefetch next K/V tile into the dead buffer (t-1's data fully consumed)
    if (it < 31) {
      const int nb = ((it + 1) & 1) * 8192;
      async16(smem + nb + lof,        gK);
      async16(smem + nb + 2048 + lof, gK + 32 * 2048);
      async16(smem + nb + 4096 + lof, gV);
      async16(smem + nb + 6144 + lof, gV + 32 * 2048);
      gK += (long)64 * 2048;
      gV += 64;
    }

    __builtin_amdgcn_s_setprio(1);
    // skewed PV(t-1) + row-sum: pure-register MFMAs, independent of K-read
    if (it > 0) {
      accA = __builtin_amdgcn_mfma_f32_32x32x16_bf16(pa0, pvA0, accA, 0, 0, 0);
      accB = __builtin_amdgcn_mfma_f32_32x32x16_bf16(pa0, pvB0, accB, 0, 0, 0);
      accA = __builtin_amdgcn_mfma_f32_32x32x16_bf16(pa1, pvA1, accA, 0, 0, 0);
      accB = __builtin_amdgcn_mfma_f32_32x32x16_bf16(pa1, pvB1, accB, 0, 0, 0);
      lsum = __builtin_amdgcn_mfma_f32_32x32x16_bf16(pa0, onesb, lsum, 0, 0, 0);
      lsum = __builtin_amdgcn_mfma_f32_32x32x16_bf16(pa1, onesb, lsum, 0, 0, 0);
    }
    // St[j in wj-half][i in wi-half]; C-in = hoisted zero (no per-iter movs)
    f32x16 st = __builtin_amdgcn_mfma_f32_32x32x16_bf16(ak[0], qf[0], fz, 0, 0, 0);
#pragma unroll
    for (int kc = 1; kc < 4; kc++)
      st = __builtin_amdgcn_mfma_f32_32x32x16_bf16(ak[kc], qf[kc], st, 0, 0, 0);
    __builtin_amdgcn_s_setprio(0);

    // V frags of CURRENT tile -> regs (used by next iteration's PV);
    // LDS latency hides under the softmax VALU chain below.
    pvA0 = *(const bf16x8*)&Vs[((l & 31)) * 64      + (((vg + hl) ^ i7) * 8)];
    pvB0 = *(const bf16x8*)&Vs[(32 + (l & 31)) * 64 + (((vg + hl) ^ i7) * 8)];
    pvA1 = *(const bf16x8*)&Vs[((l & 31)) * 64      + (((vg + 2 + hl) ^ i7) * 8)];
    pvB1 = *(const bf16x8*)&Vs[(32 + (l & 31)) * 64 + (((vg + 2 + hl) ^ i7) * 8)];

    // exp (Q pre-scaled: raw v_exp_f32 directly on St)
#pragma unroll
    for (int r = 0; r < 16; r++) st[r] = fexp2(st[r]);

    // in-register P -> bf16 A-fragments for this wave's 32 j's (2 chunks).
    unsigned int a0 = pack2(st[0],  st[1]),  b0 = pack2(st[4],  st[5]);
    unsigned int c0 = pack2(st[2],  st[3]),  d0 = pack2(st[6],  st[7]);
    unsigned int a1 = pack2(st[8],  st[9]),  b1 = pack2(st[12], st[13]);
    unsigned int c1 = pack2(st[10], st[11]), d1 = pack2(st[14], st[15]);
    plswap(a0, b0);
    plswap(c0, d0);
    plswap(a1, b1);
    plswap(c1, d1);
    const i32x4 f0 = {(int)a0, (int)c0, (int)b0, (int)d0};
    const i32x4 f1 = {(int)a1, (int)c1, (int)b1, (int)d1};
    pa0 = __builtin_bit_cast(bf16x8, f0);
    pa1 = __builtin_bit_cast(bf16x8, f1);
  }

  // drain: PV + row-sum of the last tile (register-only)
  accA = __builtin_amdgcn_mfma_f32_32x32x16_bf16(pa0, pvA0, accA, 0, 0, 0);
  accB = __builtin_amdgcn_mfma_f32_32x32x16_bf16(pa0, pvB0, accB, 0, 0, 0);
  accA = __builtin_amdgcn_mfma_f32_32x32x16_bf16(pa1, pvA1, accA, 0, 0, 0);
  accB = __builtin_amdgcn_mfma_f32_32x32x16_bf16(pa1, pvB1, accB, 0, 0, 0);
  lsum = __builtin_amdgcn_mfma_f32_32x32x16_bf16(pa0, onesb, lsum, 0, 0, 0);
  lsum = __builtin_amdgcn_mfma_f32_32x32x16_bf16(pa1, onesb, lsum, 0, 0, 0);

  // epilogue: combine partial O across the wj pair + l across wj, store.
  __syncthreads();                       // all tile reads done; LDS reusable
  float* xbf = (float*)smem;             // 4 waves x 1024 f32 = 16KB
  float* lb  = (float*)(smem + 8192);    // 128 floats (bytes 16384..16896)
#pragma unroll
  for (int r = 0; r < 16; r++)           // publish the OTHER d-half partial
    xbf[w * 1024 + r * 64 + l] = wj ? accA[r] : accB[r];
  if ((l & 31) == 0) {                   // lanes 0,32: publish own row-sums
#pragma unroll
    for (int r = 0; r < 16; r++) {
      const int iloc = (r & 3) + 8 * (r >> 2) + 4 * hl;
      lb[w * 32 + iloc] = lsum[r];
    }
  }
  __syncthreads();
  const int pw = 2 * (1 - wj) + wi;      // partner wave (same wi, other wj)
#pragma unroll
  for (int r = 0; r < 16; r++) {
    const int iloc = (r & 3) + 8 * (r >> 2) + 4 * hl;
    const float lt = lsum[r] + lb[pw * 32 + iloc];
    const float own = wj ? accB[r] : accA[r];
    const float o = own + xbf[pw * 1024 + r * 64 + l];
    const long row = q_row0 + wi * 32 + iloc;
    const long col = (long)head * 64 + wj * 32 + (l & 31);
    O[row * 1024 + col] = (__bf16)(o / lt);
  }
}

extern "C" void kernel_launch(void* const* d_in, const int* in_sizes, int n_in,
                              void* d_out, int out_size, void* d_ws, size_t ws_size,
                              hipStream_t stream) {
  const void* x    = d_in[0];
  const void* Wqkv = d_in[1];
  const void* Wout = d_in[2];
  const void* bout = d_in[3];

  char* ws = (char*)d_ws;
  int*    flagp = (int*)ws;
  __bf16* xb    = (__bf16*)(ws + 4096);                      // 8 MB (dead after gemm_qkv)
  __bf16* Obuf  = xb;                                        // alias
  __bf16* WqkvT = (__bf16*)(ws + 4096 +  8388608);           // 6 MB
  __bf16* WoutT = (__bf16*)(ws + 4096 + 14680064);           // 2 MB
  __bf16* qkbuf = (__bf16*)(ws + 4096 + 16777216);           // 16 MB
  __bf16* VtBuf = (__bf16*)(ws + 4096 + 33554432);           // 8 MB

  hipLaunchKernelGGL(prep, dim3(3072), dim3(256), 0, stream,
                     x, Wqkv, Wout, xb, WqkvT, WoutT, flagp);
  hipLaunchKernelGGL(gemm_qkv, dim3(32, 24), dim3(256), 0, stream,
                     xb, WqkvT, qkbuf, VtBuf);
  hipLaunchKernelGGL(attn_kernel, dim3(32, 32), dim3(256), 0, stream,
                     qkbuf, VtBuf, Obuf);
  hipLaunchKernelGGL(gemm_out, dim3(32, 16), dim3(256), 0, stream,
                     Obuf, WoutT, bout, d_out, flagp);
}

// Round 6
// 189.893 us; speedup vs baseline: 1.0867x; 1.0124x over previous
//
#include <hip/hip_runtime.h>

typedef __bf16 bf16x8 __attribute__((ext_vector_type(8)));
typedef __bf16 bf16x4 __attribute__((ext_vector_type(4)));
typedef __bf16 bf16x2 __attribute__((ext_vector_type(2)));
typedef float f32x4 __attribute__((ext_vector_type(4)));
typedef float f32x16 __attribute__((ext_vector_type(16)));
typedef int i32x4 __attribute__((ext_vector_type(4)));
typedef unsigned int u32x2 __attribute__((ext_vector_type(2)));

#define EXP2_SCALE 0.045084439f   // (1/32) * log2(e), folded into Q at gemm_qkv

__device__ __forceinline__ void async16(void* lds, const void* g) {
  __builtin_amdgcn_global_load_lds(
      (__attribute__((address_space(1))) unsigned int*)(g),
      (__attribute__((address_space(3))) unsigned int*)(lds), 16, 0, 0);
}

__device__ __forceinline__ unsigned int pack2(float a, float b) {
  bf16x2 t;
  t[0] = (__bf16)a;
  t[1] = (__bf16)b;
  return __builtin_bit_cast(unsigned int, t);
}

// raw v_exp_f32 (2^x): skips ocml's denormal-guard expansion.
__device__ __forceinline__ float fexp2(float x) {
#if __has_builtin(__builtin_amdgcn_exp2f)
  return __builtin_amdgcn_exp2f(x);
#else
  return exp2f(x);
#endif
}

// lane[i] <-> lane[i+32] half-wave exchange: d.hi <-> s.lo.
__device__ __forceinline__ void plswap(unsigned int& d, unsigned int& s) {
#if __has_builtin(__builtin_amdgcn_permlane32_swap)
  u32x2 r = __builtin_amdgcn_permlane32_swap(d, s, false, false);
  d = r[0];
  s = r[1];
#else
  asm("v_permlane32_swap_b32 %0, %1" : "+v"(d), "+v"(s));
#endif
}

// Per-block dtype self-detect on a 2048-u16 window.
__device__ __forceinline__ int detect_block(const unsigned short* win, int* cnt_sh) {
  if (threadIdx.x == 0) *cnt_sh = 0;
  __syncthreads();
  int c = 0;
#pragma unroll
  for (int j = 0; j < 8; j++) {
    const unsigned short u = win[threadIdx.x * 8 + j];
    if (((u >> 7) & 0xFF) >= 0xC0) c++;
  }
  if (c) atomicAdd(cnt_sh, c);
  __syncthreads();
  return (*cnt_sh >= 64) ? 1 : 0;
}

// ---------------- prep: x->bf16 cvt (blocks 0..2047, f32 path vectorized) +
// Wqkv transpose (2048..2815) + Wout transpose (2816..3071), self-detecting.
__global__ __launch_bounds__(256) void prep(
    const void* __restrict__ x, const void* __restrict__ Wqkv,
    const void* __restrict__ Wout, __bf16* __restrict__ xb,
    __bf16* __restrict__ WqkvT, __bf16* __restrict__ WoutT,
    int* __restrict__ flagp)
{
  __shared__ __bf16 tile[64 * 65];
  __shared__ int cnt;
  const int bx = blockIdx.x;
  const int t = threadIdx.x;

  if (bx < 2048) {
    const long base = (long)bx * 2048;
    const int f = detect_block((const unsigned short*)x + base, &cnt);
    if (bx == 0 && t == 0) *flagp = f;
    const long i = base + t * 8;
    if (f) {
      const f32x4* s4 = (const f32x4*)((const float*)x + i);
      const f32x4 v0 = s4[0], v1 = s4[1];
      bf16x8 o;
#pragma unroll
      for (int j = 0; j < 4; j++) o[j] = (__bf16)v0[j];
#pragma unroll
      for (int j = 0; j < 4; j++) o[4 + j] = (__bf16)v1[j];
      *(bf16x8*)&xb[i] = o;
    } else {
      *(bf16x8*)&xb[i] = *(const bf16x8*)((const __bf16*)x + i);
    }
    return;
  }

  const void* in;  __bf16* out;  int R = 1024, C, tcx, tr;
  if (bx < 2816) {
    const int idx = bx - 2048;
    in = Wqkv; out = WqkvT; C = 3072; tcx = (idx % 48) * 64; tr = (idx / 48) * 64;
  } else {
    const int idx = bx - 2816;
    in = Wout; out = WoutT; C = 1024; tcx = (idx % 16) * 64; tr = (idx / 16) * 64;
  }
  const int f = detect_block((const unsigned short*)in + (long)tr * C + tcx, &cnt);
#pragma unroll
  for (int i = 0; i < 16; i++) {
    const int idx = t + 256 * i;
    const int r = idx >> 6, c = idx & 63;
    const long g = (long)(tr + r) * C + tcx + c;
    tile[r * 65 + c] = f ? (__bf16)((const float*)in)[g] : ((const __bf16*)in)[g];
  }
  __syncthreads();
#pragma unroll
  for (int i = 0; i < 16; i++) {
    const int idx = t + 256 * i;
    const int r = idx >> 6, c = idx & 63;
    out[(long)(tcx + r) * R + tr + c] = tile[c * 65 + r];
  }
}

// ---------------- qkv GEMM: [4096,1024] x [1024,3072]^T, prefetch-pipelined.
// Epilogue writes FRAGMENT-NATIVE global layouts for attn:
//   Q  -> qbuf[row][hd]      (pre-scaled by EXP2_SCALE, stride 1024)
//   K  -> K'[bh][kt][g=d>>3][key&63][e=d&7]   (one b128 per attn A-frag)
//   V  -> V'[bh][kt][g=key>>3&7][d][e=key&7]  (one b128 per attn B-frag)
// XCD-bijective swizzle (768 = 8*96).
__global__ __launch_bounds__(256, 3) void gemm_qkv(
    const __bf16* __restrict__ A, const __bf16* __restrict__ Bt,
    __bf16* __restrict__ Qb, __bf16* __restrict__ Kc, __bf16* __restrict__ Vc)
{
  __shared__ __bf16 smem[17408];
  const int t = threadIdx.x;
  const int l = t & 63;
  const int w = t >> 6;
  const int wr = w >> 1, wc = w & 1;
  const int lid = blockIdx.y * 32 + blockIdx.x;
  const int s = (lid & 7) * 96 + (lid >> 3);
  const long m0 = (long)(s & 31) * 128;
  const long n0 = (long)(s >> 5) * 128;
  const int K = 1024;

  const int srow = w * 16 + (l >> 2);
  const int skof = (l & 3) * 8;
  const __bf16* gA = A + (m0 + srow) * (long)K + skof;
  const __bf16* gB = Bt + (n0 + srow) * (long)K + skof;
  const int Ao[2] = {0, 8192}, Bo[2] = {4096, 12288};
  const int lof = w * 512 + l * 8;

  async16(smem + Ao[0] + lof,        gA);
  async16(smem + Ao[0] + 2048 + lof, gA + 64 * (long)K);
  async16(smem + Bo[0] + lof,        gB);
  async16(smem + Bo[0] + 2048 + lof, gB + 64 * (long)K);
  gA += 32; gB += 32;
  __syncthreads();

  f32x4 acc[4][4] = {};

  for (int it = 0; it < 32; it++) {
    if (it < 31) {
      const int nb = (it + 1) & 1;
      async16(smem + Ao[nb] + lof,        gA);
      async16(smem + Ao[nb] + 2048 + lof, gA + 64 * (long)K);
      async16(smem + Bo[nb] + lof,        gB);
      async16(smem + Bo[nb] + 2048 + lof, gB + 64 * (long)K);
      gA += 32; gB += 32;
    }
    const __bf16* As = smem + Ao[it & 1];
    const __bf16* Bs = smem + Bo[it & 1];
    bf16x8 af[4], bfr[4];
#pragma unroll
    for (int mi = 0; mi < 4; mi++)
      af[mi] = *(const bf16x8*)&As[(wr * 64 + mi * 16 + (l & 15)) * 32 + (l >> 4) * 8];
#pragma unroll
    for (int ni = 0; ni < 4; ni++)
      bfr[ni] = *(const bf16x8*)&Bs[(wc * 64 + ni * 16 + (l & 15)) * 32 + (l >> 4) * 8];
#pragma unroll
    for (int mi = 0; mi < 4; mi++)
#pragma unroll
      for (int ni = 0; ni < 4; ni++)
        acc[mi][ni] = __builtin_amdgcn_mfma_f32_16x16x32_bf16(af[mi], bfr[ni], acc[mi][ni], 0, 0, 0);
    __syncthreads();
  }

  if (n0 < 1024) {                       // Q (pre-scaled, stride 1024)
#pragma unroll
    for (int mi = 0; mi < 4; mi++)
#pragma unroll
      for (int ni = 0; ni < 4; ni++) {
        const long col = n0 + wc * 64 + ni * 16 + (l & 15);
#pragma unroll
        for (int r = 0; r < 4; r++) {
          const long row = m0 + wr * 64 + mi * 16 + (l >> 4) * 4 + r;
          Qb[row * 1024 + col] = (__bf16)(acc[mi][ni][r] * EXP2_SCALE);
        }
      }
  } else if (n0 < 2048) {                // K -> fragment-native K'
    const int b = (int)(m0 >> 11);
    const int nb_ = (int)(m0 & 2047);
#pragma unroll
    for (int mi = 0; mi < 4; mi++)
#pragma unroll
      for (int ni = 0; ni < 4; ni++) {
        const int col1 = (int)(n0 - 1024) + wc * 64 + ni * 16 + (l & 15);
        const int h = col1 >> 6, d = col1 & 63;
        const long hb = ((long)(b * 16 + h) * 32);
#pragma unroll
        for (int r = 0; r < 4; r++) {
          const int n = nb_ + wr * 64 + mi * 16 + (l >> 4) * 4 + r;   // key
          const long addr = (hb + (n >> 6)) * 4096 + (d >> 3) * 512 + (n & 63) * 8 + (d & 7);
          Kc[addr] = (__bf16)acc[mi][ni][r];
        }
      }
  } else {                               // V -> fragment-native V'
#pragma unroll
    for (int mi = 0; mi < 4; mi++)
#pragma unroll
      for (int ni = 0; ni < 4; ni++) {
        const int c = wc * 64 + ni * 16 + (l & 15);
        const int r = wr * 64 + mi * 16 + (l >> 4) * 4;
        bf16x4 pk;
#pragma unroll
        for (int k = 0; k < 4; k++) pk[k] = (__bf16)acc[mi][ni][k];
        *(bf16x4*)&smem[c * 136 + r] = pk;
      }
    __syncthreads();
    const int b = (int)(m0 >> 11);
    const int nbase = (int)(m0 & 2047);
#pragma unroll
    for (int i = 0; i < 8; i++) {
      const int c = (t >> 4) + i * 16;
      const int r8 = (t & 15) * 8;
      const bf16x8 v = *(const bf16x8*)&smem[c * 136 + r8];
      const int vcol = (int)(n0 - 2048) + c;         // h*64 + d
      const int h = vcol >> 6, d = vcol & 63;
      const int n = nbase + r8;                      // key base of the 8
      const long addr = ((long)(b * 16 + h) * 32 + (n >> 6)) * 4096 + ((n >> 3) & 7) * 512 + d * 8;
      *(bf16x8*)&Vc[addr] = v;
    }
  }
}

// ---------------- out GEMM: [4096,1024] x [1024,1024]^T + bias, 128x64 tile.
__global__ __launch_bounds__(256, 2) void gemm_out(
    const __bf16* __restrict__ A, const __bf16* __restrict__ Bt,
    const void* __restrict__ bias_raw, void* __restrict__ C,
    const int* __restrict__ flagp)
{
  __shared__ __bf16 smem[12288];
  const int t = threadIdx.x;
  const int l = t & 63;
  const int w = t >> 6;
  const int wr = w >> 1, wc = w & 1;
  const int lid = blockIdx.y * 32 + blockIdx.x;
  const int s = (lid & 7) * 64 + (lid >> 3);
  const long m0 = (long)(s & 31) * 128;
  const long n0 = (long)(s >> 5) * 64;
  const int of = *flagp;
  const int K = 1024;

  const int srow = w * 16 + (l >> 2);
  const int skof = (l & 3) * 8;
  const __bf16* gA = A + (m0 + srow) * (long)K + skof;
  const __bf16* gB = Bt + (n0 + srow) * (long)K + skof;
  const int Ao[2] = {0, 6144}, Bo[2] = {4096, 10240};
  const int lof = w * 512 + l * 8;

  async16(smem + Ao[0] + lof,        gA);
  async16(smem + Ao[0] + 2048 + lof, gA + 64 * (long)K);
  async16(smem + Bo[0] + lof,        gB);
  gA += 32; gB += 32;
  __syncthreads();

  f32x4 acc[4][2] = {};

  for (int it = 0; it < 32; it++) {
    if (it < 31) {
      const int nb = (it + 1) & 1;
      async16(smem + Ao[nb] + lof,        gA);
      async16(smem + Ao[nb] + 2048 + lof, gA + 64 * (long)K);
      async16(smem + Bo[nb] + lof,        gB);
      gA += 32; gB += 32;
    }
    const __bf16* As = smem + Ao[it & 1];
    const __bf16* Bs = smem + Bo[it & 1];
    bf16x8 af[4], bfr[2];
#pragma unroll
    for (int mi = 0; mi < 4; mi++)
      af[mi] = *(const bf16x8*)&As[(wr * 64 + mi * 16 + (l & 15)) * 32 + (l >> 4) * 8];
#pragma unroll
    for (int ni = 0; ni < 2; ni++)
      bfr[ni] = *(const bf16x8*)&Bs[(wc * 32 + ni * 16 + (l & 15)) * 32 + (l >> 4) * 8];
#pragma unroll
    for (int mi = 0; mi < 4; mi++)
#pragma unroll
      for (int ni = 0; ni < 2; ni++)
        acc[mi][ni] = __builtin_amdgcn_mfma_f32_16x16x32_bf16(af[mi], bfr[ni], acc[mi][ni], 0, 0, 0);
    __syncthreads();
  }

#pragma unroll
  for (int mi = 0; mi < 4; mi++)
#pragma unroll
    for (int ni = 0; ni < 2; ni++) {
      const long col = n0 + wc * 32 + ni * 16 + (l & 15);
      const float bv = of ? ((const float*)bias_raw)[col]
                          : (float)((const __bf16*)bias_raw)[col];
#pragma unroll
      for (int r = 0; r < 4; r++) {
        const long row = m0 + wr * 64 + mi * 16 + (l >> 4) * 4 + r;
        const float val = acc[mi][ni][r] + bv;
        const long off = row * 1024 + col;
        if (of) ((float*)C)[off] = val;
        else    ((__bf16*)C)[off] = (__bf16)val;
      }
    }
}

// ---------------- flash attention, ZERO-LDS / ZERO-BARRIER main loop.
// All K/V fragments load directly from fragment-native global layouts
// (coalesced b128, L2-hot, XCD-affine). K prefetched 1 tile ahead; V of
// tile t consumed at t+1 (skewed PV, register-only MFMA cluster). Compiler
// derives counted-vmcnt waits automatically (no barrier drains). LDS used
// only for the one-time epilogue combine. Semantics of every fragment are
// identical to the R2-R5 verified kernels; only addressing changed.
__global__ __launch_bounds__(256, 3) void attn_kernel(
    const __bf16* __restrict__ Qb, const __bf16* __restrict__ Kc,
    const __bf16* __restrict__ Vc, __bf16* __restrict__ O)
{
  __shared__ float fsm[4 * 1024 + 128];
  const int t = threadIdx.x;
  const int l = t & 63;
  const int w = t >> 6;
  const int wi = w & 1, wj = w >> 1;
  const int hl = l >> 5;
  // XCD swizzle: same bh => same (linear % 8) => same XCD L2.
  const int L = blockIdx.y * 32 + blockIdx.x;
  const int bh = (L & 7) * 4 + ((L >> 3) & 3);
  const int qt = L >> 5;
  const int b = bh >> 4, head = bh & 15;
  const long q_row0 = (long)b * 2048 + qt * 64;

  // Q fragments (pre-scaled upstream), stride-1024 qbuf
  bf16x8 qf0, qf1, qf2, qf3;
  {
    const __bf16* gQ = Qb + (q_row0 + wi * 32 + (l & 31)) * 1024 + head * 64 + hl * 8;
    qf0 = *(const bf16x8*)(gQ);
    qf1 = *(const bf16x8*)(gQ + 16);
    qf2 = *(const bf16x8*)(gQ + 32);
    qf3 = *(const bf16x8*)(gQ + 48);
  }

  const __bf16* kb = Kc + (long)bh * 131072;
  const __bf16* vb = Vc + (long)bh * 131072;
  // K A-frag: (g = kc*2+hl, key = wj*32+(l&31)); frag kc offset = kof0 + kc*1024
  const int kof0 = hl * 512 + (wj * 32 + (l & 31)) * 8;
  // V B-frag: (g = wj*4 + {hl, 2+hl}, d = {l&31, 32+(l&31)})
  const int vof0 = (wj * 4 + hl) * 512 + (l & 31) * 8;   // +256 dhi, +1024 g+2

  f32x16 accA = {0,0,0,0,0,0,0,0,0,0,0,0,0,0,0,0};
  f32x16 accB = {0,0,0,0,0,0,0,0,0,0,0,0,0,0,0,0};
  const f32x16 fz = {0,0,0,0,0,0,0,0,0,0,0,0,0,0,0,0};
  float l_i = 0.0f;
  bf16x8 pa0 = {}, pa1 = {};

#define LD8(p) (*(const bf16x8*)(p))
  // tile-0 K into set a
  bf16x8 ka0 = LD8(kb + kof0),        ka1 = LD8(kb + kof0 + 1024);
  bf16x8 ka2 = LD8(kb + kof0 + 2048), ka3 = LD8(kb + kof0 + 3072);
  bf16x8 kn0, kn1, kn2, kn3;
  bf16x8 va0 = {}, va1 = {}, va2 = {}, va3 = {};
  bf16x8 vn0, vn1, vn2, vn3;

#define ATT_ITER(IT, KA0,KA1,KA2,KA3, KN0,KN1,KN2,KN3, PV0,PV1,PV2,PV3, PN0,PN1,PN2,PN3) \
  { \
    const __bf16* kt_ = kb + (IT + 1) * 4096 + kof0; \
    const __bf16* vt_ = vb + (IT) * 4096 + vof0; \
    if ((IT) < 31) { \
      KN0 = LD8(kt_); KN1 = LD8(kt_ + 1024); \
      KN2 = LD8(kt_ + 2048); KN3 = LD8(kt_ + 3072); \
    } \
    PN0 = LD8(vt_);        PN1 = LD8(vt_ + 256); \
    PN2 = LD8(vt_ + 1024); PN3 = LD8(vt_ + 1280); \
    __builtin_amdgcn_s_setprio(1); \
    if ((IT) > 0) { \
      accA = __builtin_amdgcn_mfma_f32_32x32x16_bf16(pa0, PV0, accA, 0, 0, 0); \
      accB = __builtin_amdgcn_mfma_f32_32x32x16_bf16(pa0, PV1, accB, 0, 0, 0); \
      accA = __builtin_amdgcn_mfma_f32_32x32x16_bf16(pa1, PV2, accA, 0, 0, 0); \
      accB = __builtin_amdgcn_mfma_f32_32x32x16_bf16(pa1, PV3, accB, 0, 0, 0); \
    } \
    f32x16 st = __builtin_amdgcn_mfma_f32_32x32x16_bf16(KA0, qf0, fz, 0, 0, 0); \
    st = __builtin_amdgcn_mfma_f32_32x32x16_bf16(KA1, qf1, st, 0, 0, 0); \
    st = __builtin_amdgcn_mfma_f32_32x32x16_bf16(KA2, qf2, st, 0, 0, 0); \
    st = __builtin_amdgcn_mfma_f32_32x32x16_bf16(KA3, qf3, st, 0, 0, 0); \
    __builtin_amdgcn_s_setprio(0); \
    float rs0 = 0.0f, rs1 = 0.0f; \
    _Pragma("unroll") \
    for (int r = 0; r < 16; r += 2) { \
      const float p0 = fexp2(st[r]); \
      const float p1 = fexp2(st[r + 1]); \
      st[r] = p0; st[r + 1] = p1; \
      rs0 += p0; rs1 += p1; \
    } \
    l_i += rs0 + rs1; \
    unsigned int a0 = pack2(st[0],  st[1]),  b0 = pack2(st[4],  st[5]); \
    unsigned int c0 = pack2(st[2],  st[3]),  d0 = pack2(st[6],  st[7]); \
    unsigned int a1 = pack2(st[8],  st[9]),  b1 = pack2(st[12], st[13]); \
    unsigned int c1 = pack2(st[10], st[11]), d1 = pack2(st[14], st[15]); \
    plswap(a0, b0); plswap(c0, d0); plswap(a1, b1); plswap(c1, d1); \
    const i32x4 f0_ = {(int)a0, (int)c0, (int)b0, (int)d0}; \
    const i32x4 f1_ = {(int)a1, (int)c1, (int)b1, (int)d1}; \
    pa0 = __builtin_bit_cast(bf16x8, f0_); \
    pa1 = __builtin_bit_cast(bf16x8, f1_); \
  }

  for (int itp = 0; itp < 16; itp++) {
    const int it0 = itp * 2, it1 = itp * 2 + 1;
    ATT_ITER(it0, ka0,ka1,ka2,ka3, kn0,kn1,kn2,kn3, va0,va1,va2,va3, vn0,vn1,vn2,vn3)
    ATT_ITER(it1, kn0,kn1,kn2,kn3, ka0,ka1,ka2,ka3, vn0,vn1,vn2,vn3, va0,va1,va2,va3)
  }
#undef ATT_ITER
#undef LD8

  // drain: PV of tile 31 (V set va, loaded at it=31)
  accA = __builtin_amdgcn_mfma_f32_32x32x16_bf16(pa0, va0, accA, 0, 0, 0);
  accB = __builtin_amdgcn_mfma_f32_32x32x16_bf16(pa0, va1, accB, 0, 0, 0);
  accA = __builtin_amdgcn_mfma_f32_32x32x16_bf16(pa1, va2, accA, 0, 0, 0);
  accB = __builtin_amdgcn_mfma_f32_32x32x16_bf16(pa1, va3, accB, 0, 0, 0);

  // combine l_i across the two half-waves (one permlane)
  {
    unsigned int a = __builtin_bit_cast(unsigned int, l_i), bswp = a;
    plswap(a, bswp);
    l_i = __builtin_bit_cast(float, a) + __builtin_bit_cast(float, bswp);
  }

  // epilogue: combine partial O across the wj pair + l across wj, store.
  float* xbf = fsm;                      // 4 waves x 1024 f32
  float* lb  = fsm + 4096;               // 128 floats
#pragma unroll
  for (int r = 0; r < 16; r++)           // publish the OTHER d-half partial
    xbf[w * 1024 + r * 64 + l] = wj ? accA[r] : accB[r];
  if (l < 32) lb[w * 32 + l] = l_i;
  __syncthreads();
  const int pw = 2 * (1 - wj) + wi;      // partner wave (same wi, other wj)
#pragma unroll
  for (int r = 0; r < 16; r++) {
    const int iloc = (r & 3) + 8 * (r >> 2) + 4 * hl;
    const float lt = lb[wi * 32 + iloc] + lb[(wi + 2) * 32 + iloc];
    const float own = wj ? accB[r] : accA[r];
    const float o = own + xbf[pw * 1024 + r * 64 + l];
    const long row = q_row0 + wi * 32 + iloc;
    const long col = (long)head * 64 + wj * 32 + (l & 31);
    O[row * 1024 + col] = (__bf16)(o / lt);
  }
}

extern "C" void kernel_launch(void* const* d_in, const int* in_sizes, int n_in,
                              void* d_out, int out_size, void* d_ws, size_t ws_size,
                              hipStream_t stream) {
  const void* x    = d_in[0];
  const void* Wqkv = d_in[1];
  const void* Wout = d_in[2];
  const void* bout = d_in[3];

  char* ws = (char*)d_ws;
  int*    flagp = (int*)ws;
  __bf16* xb    = (__bf16*)(ws + 4096);                      // 8 MB (dead after gemm_qkv)
  __bf16* Obuf  = xb;                                        // alias
  __bf16* WqkvT = (__bf16*)(ws + 4096 +  8388608);           // 6 MB
  __bf16* WoutT = (__bf16*)(ws + 4096 + 14680064);           // 2 MB
  __bf16* qbuf  = (__bf16*)(ws + 4096 + 16777216);           // 8 MB  Q [4096][1024]
  __bf16* kbuf  = (__bf16*)(ws + 4096 + 25165824);           // 8 MB  K' frag-native
  __bf16* vbuf  = (__bf16*)(ws + 4096 + 33554432);           // 8 MB  V' frag-native

  hipLaunchKernelGGL(prep, dim3(3072), dim3(256), 0, stream,
                     x, Wqkv, Wout, xb, WqkvT, WoutT, flagp);
  hipLaunchKernelGGL(gemm_qkv, dim3(32, 24), dim3(256), 0, stream,
                     xb, WqkvT, qbuf, kbuf, vbuf);
  hipLaunchKernelGGL(attn_kernel, dim3(32, 32), dim3(256), 0, stream,
                     qbuf, kbuf, vbuf, Obuf);
  hipLaunchKernelGGL(gemm_out, dim3(32, 16), dim3(256), 0, stream,
                     Obuf, WoutT, bout, d_out, flagp);
}